// Round 13
// baseline (877.439 us; speedup 1.0000x reference)
//
#include <hip/hip_runtime.h>
#include <hip/hip_bf16.h>
#include <math.h>

#define HD 128
#define N_OP 100000
#define N_L1 400000
#define NB 2048
#define CNT_TOT 1160000
#define EDG_TOT 1100000

typedef short short8 __attribute__((ext_vector_type(8)));
typedef float floatx4 __attribute__((ext_vector_type(4)));

// relation tables (from reference EDGES/OFFS)
static const int REL_E[14]    = {100000,100000,100000,100000,100000,100000,100000,100000,100000,50000,50000,20000,120000,60000};
static const int REL_DSZ[14]  = {100000,100000,100000,100000,100000,100000,60000,100000,100000,50000,50000,20000,120000,60000};
static const int CNT_OFF[14]  = {0,100000,200000,300000,400000,500000,600000,660000,760000,860000,910000,960000,980000,1100000};
static const int SRC_T[14] = {1,3,2,2,0,4,4,5,6,5,6,1,2,3};
static const int TF[7]  = {4,2,10,4,8,1,1};
static const size_t AGR_OFF[14] = {0,200000,600000,1600000,2600000,3000000,3800000,4280000,4380000,0,0,4480000,4520000,5720000};
#define AGR_TOT 5960000
// WL1 packed blob row offsets (rows of 128 floats); bias row last per type
static const int RELW[14] = {4,7,12,93,23,28,70,104,106,-1,-1,40,54,79};
static const int RELI[14] = {6,11,22,103,27,36,78,105,107,-1,-1,42,64,83};
static const int ROOTW[5] = {0,38,44,66,85};
static const int ROOTB[5] = {37,43,65,84,108};
#define WL1_ROWS 109

// ---------------- bf16 helpers ----------------
__device__ inline unsigned short f2bf(float f) {
  union { float f; unsigned int u; } v; v.f = f;
  unsigned int r = v.u + 0x7FFF + ((v.u >> 16) & 1);
  return (unsigned short)(r >> 16);
}
__device__ inline float bfu2f(unsigned short u) {
  union { unsigned int i; float f; } v; v.i = ((unsigned int)u) << 16; return v.f;
}

// ============ count: int degree counts per (rel,dst) + float batch counts ============
struct CJob { const int* dst; int coff; int E; int blk0; };
struct CPackK { CJob j[12]; int bblk0; const int* batch; float* pcnt; int nop; };

__global__ void count_k(CPackK P, int* __restrict__ ICNT) {
  int b = blockIdx.x;
  if (b >= P.bblk0) {
    int i = (b - P.bblk0) * 256 + threadIdx.x;
    if (i < P.nop) atomicAdd(&P.pcnt[P.batch[i]], 1.0f);
    return;
  }
  int ji = 0;
#pragma unroll
  for (int i = 1; i < 12; ++i) if (b >= P.j[i].blk0) ji = i;
  CJob J = P.j[ji];
  int e = (b - J.blk0) * 256 + threadIdx.x;
  if (e < J.E) atomicAdd(&ICNT[J.coff + J.dst[e]], 1);
}

// ============ scans: exclusive prefix over ICNT ============
#define SCAN_BLK 1024
__global__ void scan1(const int* __restrict__ in, int* __restrict__ out,
                      int* __restrict__ bsum, int n) {
  __shared__ int sh[256];
  int t = threadIdx.x;
  int base = blockIdx.x * SCAN_BLK + t * 4;
  int v0 = 0, v1 = 0, v2 = 0, v3 = 0;
  if (base + 3 < n) { int4 q = *(const int4*)&in[base]; v0 = q.x; v1 = q.y; v2 = q.z; v3 = q.w; }
  else {
    if (base < n) v0 = in[base];
    if (base + 1 < n) v1 = in[base + 1];
    if (base + 2 < n) v2 = in[base + 2];
    if (base + 3 < n) v3 = in[base + 3];
  }
  int ts = v0 + v1 + v2 + v3;
  sh[t] = ts; __syncthreads();
  for (int o = 1; o < 256; o <<= 1) {
    int x = (t >= o) ? sh[t - o] : 0;
    __syncthreads();
    sh[t] += x;
    __syncthreads();
  }
  int excl = sh[t] - ts;
  if (base < n) out[base] = excl;
  if (base + 1 < n) out[base + 1] = excl + v0;
  if (base + 2 < n) out[base + 2] = excl + v0 + v1;
  if (base + 3 < n) out[base + 3] = excl + v0 + v1 + v2;
  if (t == 255) bsum[blockIdx.x] = sh[255];
}

__global__ void scan2(int* __restrict__ bs, int nb) {
  __shared__ int sh[256];
  int t = threadIdx.x;
  const int C = 5;
  int v[C]; int ts = 0;
#pragma unroll
  for (int i = 0; i < C; ++i) { int idx = t * C + i; v[i] = (idx < nb) ? bs[idx] : 0; ts += v[i]; }
  sh[t] = ts; __syncthreads();
  for (int o = 1; o < 256; o <<= 1) {
    int x = (t >= o) ? sh[t - o] : 0;
    __syncthreads();
    sh[t] += x;
    __syncthreads();
  }
  int run = sh[t] - ts;
#pragma unroll
  for (int i = 0; i < C; ++i) { int idx = t * C + i; if (idx < nb) bs[idx] = run; run += v[i]; }
}

__global__ void scan3(int* __restrict__ CUR, int2* __restrict__ OFF2,
                      const int* __restrict__ ICNT, const int* __restrict__ bs, int n) {
  int i = blockIdx.x * 256 + threadIdx.x;
  if (i < n) {
    int o = CUR[i] + bs[i >> 10];
    CUR[i] = o;
    OFF2[i] = make_int2(o, ICNT[i]);
  }
}

// ============ fill: EDG[pos] = src, grouped by (rel,dst) ============
struct FJob { const int* src; const int* dst; int coff; int E; int blk0; };
struct FPackK { FJob j[12]; };

__global__ void fill_k(FPackK P, int* __restrict__ CUR, int* __restrict__ EDG) {
  int b = blockIdx.x;
  int ji = 0;
#pragma unroll
  for (int i = 1; i < 12; ++i) if (b >= P.j[i].blk0) ji = i;
  FJob J = P.j[ji];
  int e = (b - J.blk0) * 256 + threadIdx.x;
  if (e < J.E) {
    int pos = atomicAdd(&CUR[J.coff + J.dst[e]], 1);
    EDG[pos] = J.src[e];
  }
}

// ============ gather_all: one thread per (rel,dst), AGR[d,:F] = mean(x[src,:F]) ============
struct GJob { const float* x; float* agr; int coff; int D; int F; int blk0; };
struct GPack { GJob j[12]; };

template <int F>
__device__ inline void gathF(const float* __restrict__ x, float* __restrict__ agr,
                             const int* __restrict__ EDG, int2 oc, int d) {
  if (oc.y == 0) return;
  float s[F];
#pragma unroll
  for (int f = 0; f < F; ++f) s[f] = 0.f;
  for (int e = 0; e < oc.y; ++e) {
    int si = EDG[oc.x + e];
    const float* xp = &x[(size_t)si * F];
#pragma unroll
    for (int f = 0; f < F; ++f) s[f] += xp[f];
  }
  float rc = 1.0f / (float)oc.y;
  float* ap = &agr[(size_t)d * F];
#pragma unroll
  for (int f = 0; f < F; ++f) ap[f] = s[f] * rc;
}

__global__ void gather_all(GPack P, const int2* __restrict__ OFF2, const int* __restrict__ EDG) {
  int b = blockIdx.x;
  int ji = 0;
#pragma unroll
  for (int i = 1; i < 12; ++i) if (b >= P.j[i].blk0) ji = i;
  GJob J = P.j[ji];
  int d = (b - J.blk0) * 256 + threadIdx.x;
  if (d >= J.D) return;
  int2 oc = OFF2[J.coff + d];
  switch (J.F) {
    case 1:  gathF<1>(J.x, J.agr, EDG, oc, d); break;
    case 2:  gathF<2>(J.x, J.agr, EDG, oc, d); break;
    case 4:  gathF<4>(J.x, J.agr, EDG, oc, d); break;
    case 8:  gathF<8>(J.x, J.agr, EDG, oc, d); break;
    default: gathF<10>(J.x, J.agr, EDG, oc, d); break;
  }
}

// ============ weight prep: 17 combine jobs (into packed WL1) + 6 fragment-order repacks ============
struct CombJob { const float* A; const float* bin; const float* Mtx; const float* extra; float* Wout; float* bout; int F; };
struct CombPack { CombJob j[17]; };

__global__ void weights_prep(CombPack P, const float* __restrict__ c2root,
                             const float* __restrict__ c2rel, __hip_bfloat16* __restrict__ Wt) {
  int b = blockIdx.x;
  if (b < 17) {
    if (threadIdx.x >= 128) return;
    CombJob J = P.j[b];
    int c = threadIdx.x;
    for (int f = 0; f <= J.F; ++f) {
      const float* arow = (f < J.F) ? &J.A[f * HD] : J.bin;
      float s = (f < J.F) ? 0.f : (J.extra ? J.extra[c] : 0.f);
      for (int k = 0; k < HD; ++k) s = fmaf(arow[k], J.Mtx[k * HD + c], s);
      if (f < J.F) J.Wout[f * HD + c] = s;
      else J.bout[c] = s;
    }
  } else {
    const int RID[6] = {-1, 0, 1, 2, 4, 5};
    int j = b - 17;
    const float* W = (j == 0) ? c2root : (c2rel + (size_t)RID[j] * HD * HD);
    __hip_bfloat16* o = Wt + (size_t)j * 16384;
    for (int i = threadIdx.x; i < 16384; i += 256) {
      int i8 = i & 7;
      int ln = (i >> 3) & 63;
      int k4 = (i >> 9) & 3;
      int nt = i >> 11;
      int ln15 = ln & 15, quad = ln >> 4;
      int k = k4 * 32 + quad * 8 + i8;
      int n = nt * 16 + ln15;
      o[i] = __float2bfloat16(W[k * 128 + n]);
    }
  }
}

// ============ layer-1 v5: LDS weights, 4 rows/wave, VECTORIZED s-loads ============
struct L1v2 {
  const float* x0; const float* x1; const float* x2; const float* x3; const float* x4;
  const float* AGR; const float* WL1; const int2* OFF2;
  const float* g; const float* b;
  unsigned short* Hb;
};

__device__ inline void ldv2(float* s, const float* __restrict__ p) {
  float2 v = *(const float2*)p; s[0] = v.x; s[1] = v.y;
}
__device__ inline void ldv4(float* s, const float* __restrict__ p) {
  float4 v = *(const float4*)p; s[0] = v.x; s[1] = v.y; s[2] = v.z; s[3] = v.w;
}
__device__ inline void relF1(float* s, const float* __restrict__ agr,
                             const int2* __restrict__ OFF2, int cb, int row) {
  if (OFF2[cb + row].y > 0) { s[0] = agr[row]; s[1] = 1.f; }
  else { s[0] = 0.f; s[1] = 0.f; }
}
__device__ inline void relF2(float* s, const float* __restrict__ agr,
                             const int2* __restrict__ OFF2, int cb, int row) {
  if (OFF2[cb + row].y > 0) { ldv2(s, &agr[(size_t)row * 2]); s[2] = 1.f; }
  else { s[0] = s[1] = s[2] = 0.f; }
}
__device__ inline void relF4(float* s, const float* __restrict__ agr,
                             const int2* __restrict__ OFF2, int cb, int row) {
  if (OFF2[cb + row].y > 0) { ldv4(s, &agr[(size_t)row * 4]); s[4] = 1.f; }
  else {
#pragma unroll
    for (int f = 0; f < 5; ++f) s[f] = 0.f;
  }
}
__device__ inline void relF8(float* s, const float* __restrict__ agr,
                             const int2* __restrict__ OFF2, int cb, int row) {
  if (OFF2[cb + row].y > 0) {
    ldv4(s, &agr[(size_t)row * 8]); ldv4(s + 4, &agr[(size_t)row * 8 + 4]); s[8] = 1.f;
  } else {
#pragma unroll
    for (int f = 0; f < 9; ++f) s[f] = 0.f;
  }
}
__device__ inline void relF10(float* s, const float* __restrict__ agr,
                              const int2* __restrict__ OFF2, int cb, int row) {
  if (OFF2[cb + row].y > 0) {
    const float* p = &agr[(size_t)row * 10];
#pragma unroll
    for (int j = 0; j < 5; ++j) ldv2(s + 2 * j, p + 2 * j);
    s[10] = 1.f;
  } else {
#pragma unroll
    for (int f = 0; f < 11; ++f) s[f] = 0.f;
  }
}

template <int KT>
__device__ inline void l1_dot8(const float* __restrict__ Ls, const float (&s)[KT],
                               int c4, float (&a)[8]) {
  {
    float4 w0 = *(const float4*)&Ls[KT * 128 + c4];
    float4 w1 = *(const float4*)&Ls[KT * 128 + c4 + 64];
    a[0] = w0.x; a[1] = w0.y; a[2] = w0.z; a[3] = w0.w;
    a[4] = w1.x; a[5] = w1.y; a[6] = w1.z; a[7] = w1.w;
  }
#pragma unroll
  for (int k = 0; k < KT; ++k) {
    float4 w0 = *(const float4*)&Ls[k * 128 + c4];
    float4 w1 = *(const float4*)&Ls[k * 128 + c4 + 64];
    a[0] = fmaf(s[k], w0.x, a[0]); a[1] = fmaf(s[k], w0.y, a[1]);
    a[2] = fmaf(s[k], w0.z, a[2]); a[3] = fmaf(s[k], w0.w, a[3]);
    a[4] = fmaf(s[k], w1.x, a[4]); a[5] = fmaf(s[k], w1.y, a[5]);
    a[6] = fmaf(s[k], w1.z, a[6]); a[7] = fmaf(s[k], w1.w, a[7]);
  }
}

__device__ inline void l1_fin8(float (&a)[8], int c4, const float* __restrict__ g,
                               const float* __restrict__ bb,
                               unsigned short* __restrict__ Hb, int orow) {
  float p = 0.f, q = 0.f;
#pragma unroll
  for (int j = 0; j < 8; ++j) {
    a[j] = (a[j] > 0.f) ? a[j] : (expf(a[j]) - 1.f);
    p += a[j]; q += a[j] * a[j];
  }
#pragma unroll
  for (int m = 8; m >= 1; m >>= 1) {
    p += __shfl_xor(p, m, 64);
    q += __shfl_xor(q, m, 64);
  }
  float mean = p * (1.0f / HD);
  float var = q * (1.0f / HD) - mean * mean;
  float rstd = rsqrtf(var + 1e-5f);
  float4 g0 = *(const float4*)&g[c4], g1 = *(const float4*)&g[c4 + 64];
  float4 b0 = *(const float4*)&bb[c4], b1 = *(const float4*)&bb[c4 + 64];
  float gg[8] = {g0.x, g0.y, g0.z, g0.w, g1.x, g1.y, g1.z, g1.w};
  float bv[8] = {b0.x, b0.y, b0.z, b0.w, b1.x, b1.y, b1.z, b1.w};
  float o[8];
#pragma unroll
  for (int j = 0; j < 8; ++j) o[j] = (a[j] - mean) * rstd * gg[j] + bv[j];
  uint2 lo, hi;
  lo.x = (unsigned int)f2bf(o[0]) | ((unsigned int)f2bf(o[1]) << 16);
  lo.y = (unsigned int)f2bf(o[2]) | ((unsigned int)f2bf(o[3]) << 16);
  hi.x = (unsigned int)f2bf(o[4]) | ((unsigned int)f2bf(o[5]) << 16);
  hi.y = (unsigned int)f2bf(o[6]) | ((unsigned int)f2bf(o[7]) << 16);
  *(uint2*)&Hb[(size_t)orow * HD + c4] = lo;
  *(uint2*)&Hb[(size_t)orow * HD + c4 + 64] = hi;
}

__global__ __launch_bounds__(256) void layer1_v5(L1v2 A) {
  __shared__ float Ls[38 * 128];
  const int b = blockIdx.x, t = threadIdx.x;
  const int wv = t >> 6, ln = t & 63;
  const int sub = ln >> 4, c4 = (ln & 15) * 4;
  int type, seg;
  if (b < 1563) { type = 0; seg = b; }
  else if (b < 1876) { type = 1; seg = b - 1563; }
  else if (b < 3751) { type = 2; seg = b - 1876; }
  else if (b < 4689) { type = 3; seg = b - 3751; }
  else { type = 4; seg = b - 4689; }
  const int NR[5] = {38, 6, 22, 19, 24};
  const int RB[5] = {0, 38, 44, 66, 85};
  const int TR[5] = {100000, 20000, 120000, 60000, 100000};
  const int OB[5] = {0, 100000, 120000, 240000, 300000};
  {
    const float4* src = (const float4*)(A.WL1 + RB[type] * 128);
    float4* dst = (float4*)Ls;
    int n4 = NR[type] * 32;
    for (int i = t; i < n4; i += 256) dst[i] = src[i];
  }
  __syncthreads();
  const int row0 = seg * 64, M = TR[type], ob = OB[type];

  if (type == 0) {
#pragma unroll
    for (int it = 0; it < 4; ++it) {
      int row = row0 + it * 16 + wv * 4 + sub;
      if (row >= M) continue;
      float s[37];
      ldv4(s, &A.x0[(size_t)row * 4]);
      relF2(s + 4, A.AGR + 0, A.OFF2, 0, row);
      relF4(s + 7, A.AGR + 200000, A.OFF2, 100000, row);
      relF10(s + 12, A.AGR + 600000, A.OFF2, 200000, row);
      relF4(s + 23, A.AGR + 2600000, A.OFF2, 400000, row);
      relF8(s + 28, A.AGR + 3000000, A.OFF2, 500000, row);
      float a[8];
      l1_dot8<37>(Ls, s, c4, a);
      l1_fin8(a, c4, A.g, A.b, A.Hb, ob + row);
    }
  } else if (type == 1) {
#pragma unroll
    for (int it = 0; it < 4; ++it) {
      int row = row0 + it * 16 + wv * 4 + sub;
      if (row >= M) continue;
      float s[5];
      ldv2(s, &A.x1[(size_t)row * 2]);
      relF2(s + 2, A.AGR + 4480000, A.OFF2, 960000, row);
      float a[8];
      l1_dot8<5>(Ls, s, c4, a);
      l1_fin8(a, c4, A.g, A.b, A.Hb, ob + row);
    }
  } else if (type == 2) {
#pragma unroll
    for (int it = 0; it < 4; ++it) {
      int row = row0 + it * 16 + wv * 4 + sub;
      if (row >= M) continue;
      float s[21];
      const float* p = &A.x2[(size_t)row * 10];
#pragma unroll
      for (int j = 0; j < 5; ++j) ldv2(s + 2 * j, p + 2 * j);
      relF10(s + 10, A.AGR + 4520000, A.OFF2, 980000, row);
      float a[8];
      l1_dot8<21>(Ls, s, c4, a);
      l1_fin8(a, c4, A.g, A.b, A.Hb, ob + row);
    }
  } else if (type == 3) {
#pragma unroll
    for (int it = 0; it < 4; ++it) {
      int row = row0 + it * 16 + wv * 4 + sub;
      if (row >= M) continue;
      float s[18];
      ldv4(s, &A.x3[(size_t)row * 4]);
      relF8(s + 4, A.AGR + 3800000, A.OFF2, 600000, row);
      relF4(s + 13, A.AGR + 5720000, A.OFF2, 1100000, row);
      float a[8];
      l1_dot8<18>(Ls, s, c4, a);
      l1_fin8(a, c4, A.g, A.b, A.Hb, ob + row);
    }
  } else {
#pragma unroll
    for (int it = 0; it < 4; ++it) {
      int row = row0 + it * 16 + wv * 4 + sub;
      if (row >= M) continue;
      float s[23];
      ldv4(s, &A.x4[(size_t)row * 8]);
      ldv4(s + 4, &A.x4[(size_t)row * 8 + 4]);
      relF10(s + 8, A.AGR + 1600000, A.OFF2, 300000, row);
      relF1(s + 19, A.AGR + 4280000, A.OFF2, 660000, row);
      relF1(s + 21, A.AGR + 4380000, A.OFF2, 760000, row);
      float a[8];
      l1_dot8<23>(Ls, s, c4, a);
      l1_fin8(a, c4, A.g, A.b, A.Hb, ob + row);
    }
  }
}

// ============ layer-2 v5: 16 rows/block, terms SPLIT across 4 waves, LDS merge ============
// w0: root + rel0; w1: rel1; w2: rel2; w3: rel3 + rel4. Merge partial C via ds_add_f32,
// then fused ELU+LN+dot+pool epilogue (one 16-lane group per row).
__global__ __launch_bounds__(256, 4)
void l2_fused(const unsigned short* __restrict__ Hb, const unsigned short* __restrict__ Wt,
              const int2* __restrict__ OFF2, const int* __restrict__ EDG,
              const float* __restrict__ c2bias, const float* __restrict__ n2g,
              const float* __restrict__ n2b, const float* __restrict__ Wl,
              const int* __restrict__ batch, float* __restrict__ accb, int M) {
  const int CSR_OFF[5] = {0, 100000, 200000, 400000, 500000};   // rels 0,1,2,4,5
  const int SOFF[5]    = {100000, 240000, 120000, 0, 300000};   // Hb row offset of src type
  __shared__ float Csh[16 * 132];   // 8.4 KB merge tile (stride 132: bank-spread)
  const int t = threadIdx.x, wv = t >> 6, ln = t & 63;
  const int quad = ln >> 4, ln15 = ln & 15, q8 = quad * 8;
  const int m0 = blockIdx.x * 16;
  const int rowA = m0 + ln15;

  // zero merge tile before any atomic
  for (int i = t; i < 16 * 132; i += 256) Csh[i] = 0.f;

  // term list for this wave: -1 = root, 0..4 = relation index
  int tl0, tl1, ntm;
  if (wv == 0)      { tl0 = -1; tl1 = 0; ntm = 2; }
  else if (wv == 1) { tl0 = 1;  tl1 = 0; ntm = 1; }
  else if (wv == 2) { tl0 = 2;  tl1 = 0; ntm = 1; }
  else              { tl0 = 3;  tl1 = 4; ntm = 2; }

  floatx4 acc[8];
#pragma unroll
  for (int b = 0; b < 8; ++b) acc[b] = (floatx4){0.f, 0.f, 0.f, 0.f};

  for (int q = 0; q < ntm; ++q) {
    int tl = (q == 0) ? tl0 : tl1;
    short8 afr[4];
    if (tl < 0) {
      // root term: direct Hb row
      if (rowA < M) {
#pragma unroll
        for (int k4 = 0; k4 < 4; ++k4)
          afr[k4] = *(const short8*)&Hb[(size_t)rowA * HD + k4 * 32 + q8];
      } else {
#pragma unroll
        for (int k4 = 0; k4 < 4; ++k4)
#pragma unroll
          for (int j = 0; j < 8; ++j) afr[k4][j] = 0;
      }
    } else {
      float sum[4][8];
#pragma unroll
      for (int k4 = 0; k4 < 4; ++k4)
#pragma unroll
        for (int j = 0; j < 8; ++j) sum[k4][j] = 0.f;
      int2 oc = (rowA < M) ? OFF2[CSR_OFF[tl] + rowA] : make_int2(0, 0);
      if (oc.y > 0) {
        int so = SOFF[tl];
        for (int e = 0; e < oc.y; ++e) {
          size_t s = (size_t)(EDG[oc.x + e] + so);
#pragma unroll
          for (int k4 = 0; k4 < 4; ++k4) {
            short8 h = *(const short8*)&Hb[s * HD + k4 * 32 + q8];
#pragma unroll
            for (int j = 0; j < 8; ++j) sum[k4][j] += bfu2f((unsigned short)h[j]);
          }
        }
        float rc = 1.0f / (float)oc.y;
#pragma unroll
        for (int k4 = 0; k4 < 4; ++k4)
#pragma unroll
          for (int j = 0; j < 8; ++j) sum[k4][j] *= rc;
      }
#pragma unroll
      for (int k4 = 0; k4 < 4; ++k4)
#pragma unroll
        for (int j = 0; j < 8; ++j) afr[k4][j] = (short)f2bf(sum[k4][j]);
    }

    // B-fragments from global fragment-order blob; term index = tl+1
    const unsigned short* wb = Wt + (size_t)(tl + 1) * 16384 + (size_t)ln * 8;
#pragma unroll
    for (int nt = 0; nt < 8; ++nt) {
      short8 b0 = *(const short8*)(wb + nt * 2048 + 0 * 512);
      short8 b1 = *(const short8*)(wb + nt * 2048 + 1 * 512);
      short8 b2 = *(const short8*)(wb + nt * 2048 + 2 * 512);
      short8 b3 = *(const short8*)(wb + nt * 2048 + 3 * 512);
      acc[nt] = __builtin_amdgcn_mfma_f32_16x16x32_bf16(afr[0], b0, acc[nt], 0, 0, 0);
      acc[nt] = __builtin_amdgcn_mfma_f32_16x16x32_bf16(afr[1], b1, acc[nt], 0, 0, 0);
      acc[nt] = __builtin_amdgcn_mfma_f32_16x16x32_bf16(afr[2], b2, acc[nt], 0, 0, 0);
      acc[nt] = __builtin_amdgcn_mfma_f32_16x16x32_bf16(afr[3], b3, acc[nt], 0, 0, 0);
    }
  }

  __syncthreads();   // zero visible + all waves' acc ready
  // merge: D row = quad*4+r, col = nt*16+ln15
#pragma unroll
  for (int nt = 0; nt < 8; ++nt)
#pragma unroll
    for (int r = 0; r < 4; ++r)
      atomicAdd(&Csh[(quad * 4 + r) * 132 + nt * 16 + ln15], acc[nt][r]);
  __syncthreads();

  // epilogue: 16-lane group g handles row m0+g; thread covers 8 cols
  {
    int g = t >> 4, i15 = t & 15, cb = i15 * 8;
    int rowD = m0 + g;
    float4 wl0 = *(const float4*)&Wl[cb],    wl1 = *(const float4*)&Wl[cb + 4];
    float4 gg0 = *(const float4*)&n2g[cb],   gg1 = *(const float4*)&n2g[cb + 4];
    float4 nb0 = *(const float4*)&n2b[cb],   nb1 = *(const float4*)&n2b[cb + 4];
    float4 bc0 = *(const float4*)&c2bias[cb], bc1 = *(const float4*)&c2bias[cb + 4];
    float wlv[8] = {wl0.x, wl0.y, wl0.z, wl0.w, wl1.x, wl1.y, wl1.z, wl1.w};
    float ggv[8] = {gg0.x, gg0.y, gg0.z, gg0.w, gg1.x, gg1.y, gg1.z, gg1.w};
    float nbv[8] = {nb0.x, nb0.y, nb0.z, nb0.w, nb1.x, nb1.y, nb1.z, nb1.w};
    float bcv[8] = {bc0.x, bc0.y, bc0.z, bc0.w, bc1.x, bc1.y, bc1.z, bc1.w};
    float p = 0.f, q = 0.f, s1 = 0.f, pg = 0.f, pb = 0.f;
#pragma unroll
    for (int j = 0; j < 8; ++j) {
      float v = Csh[g * 132 + cb + j] + bcv[j];
      float e = (v > 0.f) ? v : (expf(v) - 1.f);
      float gw = ggv[j] * wlv[j];
      p += e; q += e * e; s1 += e * gw;
      pg += gw; pb += nbv[j] * wlv[j];
    }
#pragma unroll
    for (int m = 8; m >= 1; m >>= 1) {
      p += __shfl_xor(p, m, 64);
      q += __shfl_xor(q, m, 64);
      s1 += __shfl_xor(s1, m, 64);
      pg += __shfl_xor(pg, m, 64);
      pb += __shfl_xor(pb, m, 64);
    }
    if (i15 == 0 && rowD < M) {
      float mean = p * (1.0f / HD);
      float var = q * (1.0f / HD) - mean * mean;
      float rstd = rsqrtf(var + 1e-5f);
      float o = rstd * (s1 - mean * pg) + pb;
      atomicAdd(&accb[batch[rowD]], o);
    }
  }
}

__global__ void final_kernel(const float* __restrict__ accb, const float* __restrict__ pcnt,
                             const float* __restrict__ bl, float* __restrict__ out) {
  int b = blockIdx.x * 256 + threadIdx.x;
  if (b < NB) out[b] = accb[b] / fmaxf(pcnt[b], 1.0f) + bl[0];
}

// =================== host ===================
extern "C" void kernel_launch(void* const* d_in, const int* in_sizes, int n_in,
                              void* d_out, int out_size, void* d_ws, size_t ws_size,
                              hipStream_t stream) {
  const float* xt[7];
  for (int t = 0; t < 7; ++t) xt[t] = (const float*)d_in[t];
  const int* ei[14];
  for (int r = 0; r < 14; ++r) ei[r] = (const int*)d_in[7 + r];
  const int* batch = (const int*)d_in[21];
  const float* Wemb[7]; const float* bemb[7];
  for (int t = 0; t < 7; ++t) { Wemb[t] = (const float*)d_in[22 + 2 * t]; bemb[t] = (const float*)d_in[23 + 2 * t]; }
  const float* c_root[2] = {(const float*)d_in[36], (const float*)d_in[39]};
  const float* c_rel[2]  = {(const float*)d_in[37], (const float*)d_in[40]};
  const float* c_bias[2] = {(const float*)d_in[38], (const float*)d_in[41]};
  const float* ng[2] = {(const float*)d_in[42], (const float*)d_in[44]};
  const float* nbv[2] = {(const float*)d_in[43], (const float*)d_in[45]};
  const float* Wlin = (const float*)d_in[46];
  const float* blin = (const float*)d_in[47];
  float* out = (float*)d_out;

  char* base = (char*)d_ws;
  size_t off = 0;
  auto alloc = [&](size_t bytes) -> void* {
    void* p = base + off;
    off += (bytes + 255) & ~(size_t)255;
    return p;
  };
  __hip_bfloat16* Hb = (__hip_bfloat16*)alloc((size_t)N_L1 * HD * 2);
  float* AGR  = (float*)alloc((size_t)AGR_TOT * 4);
  int*   ICNT = (int*)alloc((size_t)CNT_TOT * 4);
  int*   CUR  = (int*)alloc((size_t)CNT_TOT * 4);
  int2*  OFF2 = (int2*)alloc((size_t)CNT_TOT * 8);
  int*   EDG  = (int*)alloc((size_t)EDG_TOT * 4);
  int*   BS   = (int*)alloc((size_t)1152 * 4);
  float* WL1  = (float*)alloc((size_t)WL1_ROWS * 128 * 4);
  __hip_bfloat16* WT3 = (__hip_bfloat16*)alloc((size_t)6 * 16384 * 2);
  float* ACC  = (float*)alloc((size_t)NB * 4);      // ACC and PCNT adjacent:
  float* PCNT = (float*)alloc((size_t)NB * 4);      // one memset covers both

  static const int l1_rels[12] = {0,1,2,3,4,5,6,7,8,11,12,13};

  // ---- memsets (2) ----
  hipMemsetAsync(ICNT, 0, (size_t)CNT_TOT * 4, stream);
  hipMemsetAsync(ACC, 0, (size_t)2 * NB * 4, stream);

  // ---- count (incl. batch counts) ----
  CPackK CP1;
  int blk = 0;
  for (int q = 0; q < 12; ++q) {
    int r = l1_rels[q];
    CP1.j[q].dst = ei[r] + REL_E[r];
    CP1.j[q].coff = CNT_OFF[r];
    CP1.j[q].E = REL_E[r];
    CP1.j[q].blk0 = blk;
    blk += (REL_E[r] + 255) / 256;
  }
  CP1.bblk0 = blk; CP1.batch = batch; CP1.pcnt = PCNT; CP1.nop = N_OP;
  blk += (N_OP + 255) / 256;
  count_k<<<blk, 256, 0, stream>>>(CP1, ICNT);

  // ---- scan -> CUR (running offsets), OFF2 (off,cnt) ----
  int nb1 = (CNT_TOT + SCAN_BLK - 1) / SCAN_BLK;   // 1133
  scan1<<<nb1, 256, 0, stream>>>(ICNT, CUR, BS, CNT_TOT);
  scan2<<<1, 256, 0, stream>>>(BS, nb1);
  scan3<<<(CNT_TOT + 255) / 256, 256, 0, stream>>>(CUR, OFF2, ICNT, BS, CNT_TOT);

  // ---- fill CSR ----
  FPackK FP;
  blk = 0;
  for (int q = 0; q < 12; ++q) {
    int r = l1_rels[q];
    FP.j[q].src = ei[r];
    FP.j[q].dst = ei[r] + REL_E[r];
    FP.j[q].coff = CNT_OFF[r];
    FP.j[q].E = REL_E[r];
    FP.j[q].blk0 = blk;
    blk += (REL_E[r] + 255) / 256;
  }
  fill_k<<<blk, 256, 0, stream>>>(FP, CUR, EDG);

  // ---- weights: 12 rel-combine + 5 root-combine (into packed WL1) + 6 fragment repacks ----
  CombPack CP;
  for (int q = 0; q < 12; ++q) {
    int r = l1_rels[q]; int t = SRC_T[r];
    CombJob& J = CP.j[q];
    J.A = Wemb[t]; J.bin = bemb[t]; J.Mtx = c_rel[0] + (size_t)r * HD * HD;
    J.extra = nullptr;
    J.Wout = WL1 + (size_t)RELW[r] * 128;
    J.bout = WL1 + (size_t)RELI[r] * 128;
    J.F = TF[t];
  }
  for (int t = 0; t < 5; ++t) {
    CombJob& J = CP.j[12 + t];
    J.A = Wemb[t]; J.bin = bemb[t]; J.Mtx = c_root[0];
    J.extra = c_bias[0];
    J.Wout = WL1 + (size_t)ROOTW[t] * 128;
    J.bout = WL1 + (size_t)ROOTB[t] * 128;
    J.F = TF[t];
  }
  weights_prep<<<23, 256, 0, stream>>>(CP, c_root[1], c_rel[1], WT3);

  // ---- gather: one thread per (rel,dst), writes pre-averaged AGR ----
  GPack GP;
  blk = 0;
  for (int q = 0; q < 12; ++q) {
    int r = l1_rels[q]; int t = SRC_T[r];
    GP.j[q].x = xt[t];
    GP.j[q].agr = AGR + AGR_OFF[r];
    GP.j[q].coff = CNT_OFF[r];
    GP.j[q].D = REL_DSZ[r];
    GP.j[q].F = TF[t];
    GP.j[q].blk0 = blk;
    blk += (REL_DSZ[r] + 255) / 256;
  }
  gather_all<<<blk, 256, 0, stream>>>(GP, OFF2, EDG);

  // ---- layer 1: 4 rows/wave, vectorized s-loads (v5, 80 VGPR) ----
  L1v2 A;
  A.x0 = xt[0]; A.x1 = xt[1]; A.x2 = xt[2]; A.x3 = xt[3]; A.x4 = xt[4];
  A.AGR = AGR; A.WL1 = WL1; A.OFF2 = OFF2;
  A.g = ng[0]; A.b = nbv[0]; A.Hb = (unsigned short*)Hb;
  layer1_v5<<<6252, 256, 0, stream>>>(A);

  // ---- layer 2: 16 rows/block, term-split waves, LDS merge ----
  l2_fused<<<(N_OP + 15) / 16, 256, 0, stream>>>(
      (const unsigned short*)Hb, (const unsigned short*)WT3,
      OFF2, EDG, c_bias[1], ng[1], nbv[1], Wlin, batch, ACC, N_OP);

  // ---- final scale ----
  final_kernel<<<(NB + 255) / 256, 256, 0, stream>>>(ACC, PCNT, blin, out);
}

// Round 14
// 602.935 us; speedup vs baseline: 1.4553x; 1.4553x over previous
//
#include <hip/hip_runtime.h>
#include <hip/hip_bf16.h>
#include <math.h>

#define HD 128
#define N_OP 100000
#define N_L1 400000
#define NB 2048
#define CNT_TOT 1160000
#define EDG_TOT 1100000

typedef short short8 __attribute__((ext_vector_type(8)));
typedef float floatx4 __attribute__((ext_vector_type(4)));

// relation tables (from reference EDGES/OFFS)
static const int REL_E[14]    = {100000,100000,100000,100000,100000,100000,100000,100000,100000,50000,50000,20000,120000,60000};
static const int REL_DSZ[14]  = {100000,100000,100000,100000,100000,100000,60000,100000,100000,50000,50000,20000,120000,60000};
static const int CNT_OFF[14]  = {0,100000,200000,300000,400000,500000,600000,660000,760000,860000,910000,960000,980000,1100000};
static const int SRC_T[14] = {1,3,2,2,0,4,4,5,6,5,6,1,2,3};
static const int TF[7]  = {4,2,10,4,8,1,1};
static const size_t AGR_OFF[14] = {0,200000,600000,1600000,2600000,3000000,3800000,4280000,4380000,0,0,4480000,4520000,5720000};
#define AGR_TOT 5960000
// WL1 packed blob row offsets (rows of 128 floats); bias row last per type
static const int RELW[14] = {4,7,12,93,23,28,70,104,106,-1,-1,40,54,79};
static const int RELI[14] = {6,11,22,103,27,36,78,105,107,-1,-1,42,64,83};
static const int ROOTW[5] = {0,38,44,66,85};
static const int ROOTB[5] = {37,43,65,84,108};
#define WL1_ROWS 109

// ---------------- bf16 helpers ----------------
__device__ inline unsigned short f2bf(float f) {
  union { float f; unsigned int u; } v; v.f = f;
  unsigned int r = v.u + 0x7FFF + ((v.u >> 16) & 1);
  return (unsigned short)(r >> 16);
}
__device__ inline float bfu2f(unsigned short u) {
  union { unsigned int i; float f; } v; v.i = ((unsigned int)u) << 16; return v.f;
}

// ============ prep: 12 edge-count jobs + batch counts + 17 combine + 6 repack, ONE kernel ============
struct CJob { const int* dst; int coff; int E; int blk0; };
struct CombJob { const float* A; const float* bin; const float* Mtx; const float* extra; float* Wout; float* bout; int F; };
struct PrepPack {
  CJob j[12];
  int bblk0;      // first block of batch-count range
  int wstart;     // first block of weights range
  const int* batch; float* pcnt; int nop;
  CombJob c[17];
};

__global__ void prep_k(PrepPack P, const float* __restrict__ c2root,
                       const float* __restrict__ c2rel, __hip_bfloat16* __restrict__ Wt,
                       int* __restrict__ ICNT) {
  int b = blockIdx.x;
  if (b >= P.wstart) {
    int wj = b - P.wstart;
    if (wj < 17) {
      if (threadIdx.x >= 128) return;
      CombJob J = P.c[wj];
      int c = threadIdx.x;
      for (int f = 0; f <= J.F; ++f) {
        const float* arow = (f < J.F) ? &J.A[f * HD] : J.bin;
        float s = (f < J.F) ? 0.f : (J.extra ? J.extra[c] : 0.f);
        for (int k = 0; k < HD; ++k) s = fmaf(arow[k], J.Mtx[k * HD + c], s);
        if (f < J.F) J.Wout[f * HD + c] = s;
        else J.bout[c] = s;
      }
    } else {
      const int RID[6] = {-1, 0, 1, 2, 4, 5};
      int j = wj - 17;
      const float* W = (j == 0) ? c2root : (c2rel + (size_t)RID[j] * HD * HD);
      __hip_bfloat16* o = Wt + (size_t)j * 16384;
      for (int i = threadIdx.x; i < 16384; i += 256) {
        int i8 = i & 7;
        int ln = (i >> 3) & 63;
        int k4 = (i >> 9) & 3;
        int nt = i >> 11;
        int ln15 = ln & 15, quad = ln >> 4;
        int k = k4 * 32 + quad * 8 + i8;
        int n = nt * 16 + ln15;
        o[i] = __float2bfloat16(W[k * 128 + n]);
      }
    }
    return;
  }
  if (b >= P.bblk0) {
    int i = (b - P.bblk0) * 256 + threadIdx.x;
    if (i < P.nop) atomicAdd(&P.pcnt[P.batch[i]], 1.0f);
    return;
  }
  int ji = 0;
#pragma unroll
  for (int i = 1; i < 12; ++i) if (b >= P.j[i].blk0) ji = i;
  CJob J = P.j[ji];
  int e = (b - J.blk0) * 256 + threadIdx.x;
  if (e < J.E) atomicAdd(&ICNT[J.coff + J.dst[e]], 1);
}

// ============ scans ============
#define SCAN_BLK 1024
__global__ void scan1(const int* __restrict__ in, int* __restrict__ out,
                      int* __restrict__ bsum, int n) {
  __shared__ int sh[256];
  int t = threadIdx.x;
  int base = blockIdx.x * SCAN_BLK + t * 4;
  int v0 = 0, v1 = 0, v2 = 0, v3 = 0;
  if (base + 3 < n) { int4 q = *(const int4*)&in[base]; v0 = q.x; v1 = q.y; v2 = q.z; v3 = q.w; }
  else {
    if (base < n) v0 = in[base];
    if (base + 1 < n) v1 = in[base + 1];
    if (base + 2 < n) v2 = in[base + 2];
    if (base + 3 < n) v3 = in[base + 3];
  }
  int ts = v0 + v1 + v2 + v3;
  sh[t] = ts; __syncthreads();
  for (int o = 1; o < 256; o <<= 1) {
    int x = (t >= o) ? sh[t - o] : 0;
    __syncthreads();
    sh[t] += x;
    __syncthreads();
  }
  int excl = sh[t] - ts;
  if (base < n) out[base] = excl;
  if (base + 1 < n) out[base + 1] = excl + v0;
  if (base + 2 < n) out[base + 2] = excl + v0 + v1;
  if (base + 3 < n) out[base + 3] = excl + v0 + v1 + v2;
  if (t == 255) bsum[blockIdx.x] = sh[255];
}

// per-1024-entry block: base = SUM(bs[0..j-1]) via parallel reduction (no scan2 needed)
__global__ void scan3b(int* __restrict__ CUR, int2* __restrict__ OFF2,
                       const int* __restrict__ ICNT, const int* __restrict__ bs, int n) {
  __shared__ int sh[4];
  const int j = blockIdx.x, t = threadIdx.x;
  int s = 0;
  for (int i = t; i < j; i += 256) s += bs[i];
#pragma unroll
  for (int m = 32; m >= 1; m >>= 1) s += __shfl_xor(s, m, 64);
  if ((t & 63) == 0) sh[t >> 6] = s;
  __syncthreads();
  int base = sh[0] + sh[1] + sh[2] + sh[3];
  int i0 = j * SCAN_BLK + t * 4;
#pragma unroll
  for (int k = 0; k < 4; ++k) {
    int i = i0 + k;
    if (i < n) {
      int o = CUR[i] + base;
      CUR[i] = o;
      OFF2[i] = make_int2(o, ICNT[i]);
    }
  }
}

// ============ fill: EDG[pos] = src, grouped by (rel,dst) ============
struct FJob { const int* src; const int* dst; int coff; int E; int blk0; };
struct FPackK { FJob j[12]; };

__global__ void fill_k(FPackK P, int* __restrict__ CUR, int* __restrict__ EDG) {
  int b = blockIdx.x;
  int ji = 0;
#pragma unroll
  for (int i = 1; i < 12; ++i) if (b >= P.j[i].blk0) ji = i;
  FJob J = P.j[ji];
  int e = (b - J.blk0) * 256 + threadIdx.x;
  if (e < J.E) {
    int pos = atomicAdd(&CUR[J.coff + J.dst[e]], 1);
    EDG[pos] = J.src[e];
  }
}

// ============ gather_all: one thread per (rel,dst), AGR[d,:F] = mean(x[src,:F]) ============
struct GJob { const float* x; float* agr; int coff; int D; int F; int blk0; };
struct GPack { GJob j[12]; };

template <int F>
__device__ inline void gathF(const float* __restrict__ x, float* __restrict__ agr,
                             const int* __restrict__ EDG, int2 oc, int d) {
  if (oc.y == 0) return;
  float s[F];
#pragma unroll
  for (int f = 0; f < F; ++f) s[f] = 0.f;
  for (int e = 0; e < oc.y; ++e) {
    int si = EDG[oc.x + e];
    const float* xp = &x[(size_t)si * F];
#pragma unroll
    for (int f = 0; f < F; ++f) s[f] += xp[f];
  }
  float rc = 1.0f / (float)oc.y;
  float* ap = &agr[(size_t)d * F];
#pragma unroll
  for (int f = 0; f < F; ++f) ap[f] = s[f] * rc;
}

__global__ void gather_all(GPack P, const int2* __restrict__ OFF2, const int* __restrict__ EDG) {
  int b = blockIdx.x;
  int ji = 0;
#pragma unroll
  for (int i = 1; i < 12; ++i) if (b >= P.j[i].blk0) ji = i;
  GJob J = P.j[ji];
  int d = (b - J.blk0) * 256 + threadIdx.x;
  if (d >= J.D) return;
  int2 oc = OFF2[J.coff + d];
  switch (J.F) {
    case 1:  gathF<1>(J.x, J.agr, EDG, oc, d); break;
    case 2:  gathF<2>(J.x, J.agr, EDG, oc, d); break;
    case 4:  gathF<4>(J.x, J.agr, EDG, oc, d); break;
    case 8:  gathF<8>(J.x, J.agr, EDG, oc, d); break;
    default: gathF<10>(J.x, J.agr, EDG, oc, d); break;
  }
}

// ============ layer-1 v5: LDS weights, 4 rows/wave, vectorized s-loads ============
struct L1v2 {
  const float* x0; const float* x1; const float* x2; const float* x3; const float* x4;
  const float* AGR; const float* WL1; const int2* OFF2;
  const float* g; const float* b;
  unsigned short* Hb;
};

__device__ inline void ldv2(float* s, const float* __restrict__ p) {
  float2 v = *(const float2*)p; s[0] = v.x; s[1] = v.y;
}
__device__ inline void ldv4(float* s, const float* __restrict__ p) {
  float4 v = *(const float4*)p; s[0] = v.x; s[1] = v.y; s[2] = v.z; s[3] = v.w;
}
__device__ inline void relF1(float* s, const float* __restrict__ agr,
                             const int2* __restrict__ OFF2, int cb, int row) {
  if (OFF2[cb + row].y > 0) { s[0] = agr[row]; s[1] = 1.f; }
  else { s[0] = 0.f; s[1] = 0.f; }
}
__device__ inline void relF2(float* s, const float* __restrict__ agr,
                             const int2* __restrict__ OFF2, int cb, int row) {
  if (OFF2[cb + row].y > 0) { ldv2(s, &agr[(size_t)row * 2]); s[2] = 1.f; }
  else { s[0] = s[1] = s[2] = 0.f; }
}
__device__ inline void relF4(float* s, const float* __restrict__ agr,
                             const int2* __restrict__ OFF2, int cb, int row) {
  if (OFF2[cb + row].y > 0) { ldv4(s, &agr[(size_t)row * 4]); s[4] = 1.f; }
  else {
#pragma unroll
    for (int f = 0; f < 5; ++f) s[f] = 0.f;
  }
}
__device__ inline void relF8(float* s, const float* __restrict__ agr,
                             const int2* __restrict__ OFF2, int cb, int row) {
  if (OFF2[cb + row].y > 0) {
    ldv4(s, &agr[(size_t)row * 8]); ldv4(s + 4, &agr[(size_t)row * 8 + 4]); s[8] = 1.f;
  } else {
#pragma unroll
    for (int f = 0; f < 9; ++f) s[f] = 0.f;
  }
}
__device__ inline void relF10(float* s, const float* __restrict__ agr,
                              const int2* __restrict__ OFF2, int cb, int row) {
  if (OFF2[cb + row].y > 0) {
    const float* p = &agr[(size_t)row * 10];
#pragma unroll
    for (int j = 0; j < 5; ++j) ldv2(s + 2 * j, p + 2 * j);
    s[10] = 1.f;
  } else {
#pragma unroll
    for (int f = 0; f < 11; ++f) s[f] = 0.f;
  }
}

template <int KT>
__device__ inline void l1_dot8(const float* __restrict__ Ls, const float (&s)[KT],
                               int c4, float (&a)[8]) {
  {
    float4 w0 = *(const float4*)&Ls[KT * 128 + c4];
    float4 w1 = *(const float4*)&Ls[KT * 128 + c4 + 64];
    a[0] = w0.x; a[1] = w0.y; a[2] = w0.z; a[3] = w0.w;
    a[4] = w1.x; a[5] = w1.y; a[6] = w1.z; a[7] = w1.w;
  }
#pragma unroll
  for (int k = 0; k < KT; ++k) {
    float4 w0 = *(const float4*)&Ls[k * 128 + c4];
    float4 w1 = *(const float4*)&Ls[k * 128 + c4 + 64];
    a[0] = fmaf(s[k], w0.x, a[0]); a[1] = fmaf(s[k], w0.y, a[1]);
    a[2] = fmaf(s[k], w0.z, a[2]); a[3] = fmaf(s[k], w0.w, a[3]);
    a[4] = fmaf(s[k], w1.x, a[4]); a[5] = fmaf(s[k], w1.y, a[5]);
    a[6] = fmaf(s[k], w1.z, a[6]); a[7] = fmaf(s[k], w1.w, a[7]);
  }
}

__device__ inline void l1_fin8(float (&a)[8], int c4, const float* __restrict__ g,
                               const float* __restrict__ bb,
                               unsigned short* __restrict__ Hb, int orow) {
  float p = 0.f, q = 0.f;
#pragma unroll
  for (int j = 0; j < 8; ++j) {
    a[j] = (a[j] > 0.f) ? a[j] : (expf(a[j]) - 1.f);
    p += a[j]; q += a[j] * a[j];
  }
#pragma unroll
  for (int m = 8; m >= 1; m >>= 1) {
    p += __shfl_xor(p, m, 64);
    q += __shfl_xor(q, m, 64);
  }
  float mean = p * (1.0f / HD);
  float var = q * (1.0f / HD) - mean * mean;
  float rstd = rsqrtf(var + 1e-5f);
  float4 g0 = *(const float4*)&g[c4], g1 = *(const float4*)&g[c4 + 64];
  float4 b0 = *(const float4*)&bb[c4], b1 = *(const float4*)&bb[c4 + 64];
  float gg[8] = {g0.x, g0.y, g0.z, g0.w, g1.x, g1.y, g1.z, g1.w};
  float bv[8] = {b0.x, b0.y, b0.z, b0.w, b1.x, b1.y, b1.z, b1.w};
  float o[8];
#pragma unroll
  for (int j = 0; j < 8; ++j) o[j] = (a[j] - mean) * rstd * gg[j] + bv[j];
  uint2 lo, hi;
  lo.x = (unsigned int)f2bf(o[0]) | ((unsigned int)f2bf(o[1]) << 16);
  lo.y = (unsigned int)f2bf(o[2]) | ((unsigned int)f2bf(o[3]) << 16);
  hi.x = (unsigned int)f2bf(o[4]) | ((unsigned int)f2bf(o[5]) << 16);
  hi.y = (unsigned int)f2bf(o[6]) | ((unsigned int)f2bf(o[7]) << 16);
  *(uint2*)&Hb[(size_t)orow * HD + c4] = lo;
  *(uint2*)&Hb[(size_t)orow * HD + c4 + 64] = hi;
}

__global__ __launch_bounds__(256) void layer1_v5(L1v2 A) {
  __shared__ float Ls[38 * 128];
  const int b = blockIdx.x, t = threadIdx.x;
  const int wv = t >> 6, ln = t & 63;
  const int sub = ln >> 4, c4 = (ln & 15) * 4;
  int type, seg;
  if (b < 1563) { type = 0; seg = b; }
  else if (b < 1876) { type = 1; seg = b - 1563; }
  else if (b < 3751) { type = 2; seg = b - 1876; }
  else if (b < 4689) { type = 3; seg = b - 3751; }
  else { type = 4; seg = b - 4689; }
  const int NR[5] = {38, 6, 22, 19, 24};
  const int RB[5] = {0, 38, 44, 66, 85};
  const int TR[5] = {100000, 20000, 120000, 60000, 100000};
  const int OB[5] = {0, 100000, 120000, 240000, 300000};
  {
    const float4* src = (const float4*)(A.WL1 + RB[type] * 128);
    float4* dst = (float4*)Ls;
    int n4 = NR[type] * 32;
    for (int i = t; i < n4; i += 256) dst[i] = src[i];
  }
  __syncthreads();
  const int row0 = seg * 64, M = TR[type], ob = OB[type];

  if (type == 0) {
#pragma unroll
    for (int it = 0; it < 4; ++it) {
      int row = row0 + it * 16 + wv * 4 + sub;
      if (row >= M) continue;
      float s[37];
      ldv4(s, &A.x0[(size_t)row * 4]);
      relF2(s + 4, A.AGR + 0, A.OFF2, 0, row);
      relF4(s + 7, A.AGR + 200000, A.OFF2, 100000, row);
      relF10(s + 12, A.AGR + 600000, A.OFF2, 200000, row);
      relF4(s + 23, A.AGR + 2600000, A.OFF2, 400000, row);
      relF8(s + 28, A.AGR + 3000000, A.OFF2, 500000, row);
      float a[8];
      l1_dot8<37>(Ls, s, c4, a);
      l1_fin8(a, c4, A.g, A.b, A.Hb, ob + row);
    }
  } else if (type == 1) {
#pragma unroll
    for (int it = 0; it < 4; ++it) {
      int row = row0 + it * 16 + wv * 4 + sub;
      if (row >= M) continue;
      float s[5];
      ldv2(s, &A.x1[(size_t)row * 2]);
      relF2(s + 2, A.AGR + 4480000, A.OFF2, 960000, row);
      float a[8];
      l1_dot8<5>(Ls, s, c4, a);
      l1_fin8(a, c4, A.g, A.b, A.Hb, ob + row);
    }
  } else if (type == 2) {
#pragma unroll
    for (int it = 0; it < 4; ++it) {
      int row = row0 + it * 16 + wv * 4 + sub;
      if (row >= M) continue;
      float s[21];
      const float* p = &A.x2[(size_t)row * 10];
#pragma unroll
      for (int j = 0; j < 5; ++j) ldv2(s + 2 * j, p + 2 * j);
      relF10(s + 10, A.AGR + 4520000, A.OFF2, 980000, row);
      float a[8];
      l1_dot8<21>(Ls, s, c4, a);
      l1_fin8(a, c4, A.g, A.b, A.Hb, ob + row);
    }
  } else if (type == 3) {
#pragma unroll
    for (int it = 0; it < 4; ++it) {
      int row = row0 + it * 16 + wv * 4 + sub;
      if (row >= M) continue;
      float s[18];
      ldv4(s, &A.x3[(size_t)row * 4]);
      relF8(s + 4, A.AGR + 3800000, A.OFF2, 600000, row);
      relF4(s + 13, A.AGR + 5720000, A.OFF2, 1100000, row);
      float a[8];
      l1_dot8<18>(Ls, s, c4, a);
      l1_fin8(a, c4, A.g, A.b, A.Hb, ob + row);
    }
  } else {
#pragma unroll
    for (int it = 0; it < 4; ++it) {
      int row = row0 + it * 16 + wv * 4 + sub;
      if (row >= M) continue;
      float s[23];
      ldv4(s, &A.x4[(size_t)row * 8]);
      ldv4(s + 4, &A.x4[(size_t)row * 8 + 4]);
      relF10(s + 8, A.AGR + 1600000, A.OFF2, 300000, row);
      relF1(s + 19, A.AGR + 4280000, A.OFF2, 660000, row);
      relF1(s + 21, A.AGR + 4380000, A.OFF2, 760000, row);
      float a[8];
      l1_dot8<23>(Ls, s, c4, a);
      l1_fin8(a, c4, A.g, A.b, A.Hb, ob + row);
    }
  }
}

// ============ layer-2 v3 (best known): barrier-free, no LDS; B-fragments from global ============
__global__ __launch_bounds__(256, 4)
void l2_fused(const unsigned short* __restrict__ Hb, const unsigned short* __restrict__ Wt,
              const int2* __restrict__ OFF2, const int* __restrict__ EDG,
              const float* __restrict__ c2bias, const float* __restrict__ n2g,
              const float* __restrict__ n2b, const float* __restrict__ Wl,
              const int* __restrict__ batch, float* __restrict__ accb, int M) {
  const int CSR_OFF[5] = {0, 100000, 200000, 400000, 500000};   // rels 0,1,2,4,5
  const int SOFF[5]    = {100000, 240000, 120000, 0, 300000};   // Hb row offset of src type
  const int t = threadIdx.x, wv = t >> 6, ln = t & 63;
  const int quad = ln >> 4, ln15 = ln & 15, q8 = quad * 8;
  const int m0 = blockIdx.x * 64;
  const int rowA = m0 + wv * 16 + ln15;

  int2 ocs[5];
#pragma unroll
  for (int r = 0; r < 5; ++r)
    ocs[r] = (rowA < M) ? OFF2[CSR_OFF[r] + rowA] : make_int2(0, 0);

  float bias_c[8], gw[8];
  float pg = 0.f, pb = 0.f;
#pragma unroll
  for (int nt = 0; nt < 8; ++nt) {
    int col = nt * 16 + ln15;
    float wl = Wl[col], gc = n2g[col], bc = n2b[col];
    bias_c[nt] = c2bias[col];
    gw[nt] = gc * wl;
    pg += gc * wl;
    pb += bc * wl;
  }
#pragma unroll
  for (int m = 8; m >= 1; m >>= 1) {
    pg += __shfl_xor(pg, m, 64);
    pb += __shfl_xor(pb, m, 64);
  }

  floatx4 acc[8];
#pragma unroll
  for (int b = 0; b < 8; ++b) acc[b] = (floatx4){0.f, 0.f, 0.f, 0.f};

  for (int term = 0; term < 6; ++term) {
    short8 afr[4];
    if (term == 0) {
      if (rowA < M) {
#pragma unroll
        for (int k4 = 0; k4 < 4; ++k4)
          afr[k4] = *(const short8*)&Hb[(size_t)rowA * HD + k4 * 32 + q8];
      } else {
#pragma unroll
        for (int k4 = 0; k4 < 4; ++k4)
#pragma unroll
          for (int j = 0; j < 8; ++j) afr[k4][j] = 0;
      }
    } else {
      float sum[4][8];
#pragma unroll
      for (int k4 = 0; k4 < 4; ++k4)
#pragma unroll
        for (int j = 0; j < 8; ++j) sum[k4][j] = 0.f;
      int2 oc = ocs[term - 1];
      if (oc.y > 0) {
        int so = SOFF[term - 1];
        for (int e = 0; e < oc.y; ++e) {
          size_t s = (size_t)(EDG[oc.x + e] + so);
#pragma unroll
          for (int k4 = 0; k4 < 4; ++k4) {
            short8 h = *(const short8*)&Hb[s * HD + k4 * 32 + q8];
#pragma unroll
            for (int j = 0; j < 8; ++j) sum[k4][j] += bfu2f((unsigned short)h[j]);
          }
        }
        float rc = 1.0f / (float)oc.y;
#pragma unroll
        for (int k4 = 0; k4 < 4; ++k4)
#pragma unroll
          for (int j = 0; j < 8; ++j) sum[k4][j] *= rc;
      }
#pragma unroll
      for (int k4 = 0; k4 < 4; ++k4)
#pragma unroll
        for (int j = 0; j < 8; ++j) afr[k4][j] = (short)f2bf(sum[k4][j]);
    }

    const unsigned short* wb = Wt + (size_t)term * 16384 + (size_t)ln * 8;
#pragma unroll
    for (int nt = 0; nt < 8; ++nt) {
      short8 b0 = *(const short8*)(wb + nt * 2048 + 0 * 512);
      short8 b1 = *(const short8*)(wb + nt * 2048 + 1 * 512);
      short8 b2 = *(const short8*)(wb + nt * 2048 + 2 * 512);
      short8 b3 = *(const short8*)(wb + nt * 2048 + 3 * 512);
      acc[nt] = __builtin_amdgcn_mfma_f32_16x16x32_bf16(afr[0], b0, acc[nt], 0, 0, 0);
      acc[nt] = __builtin_amdgcn_mfma_f32_16x16x32_bf16(afr[1], b1, acc[nt], 0, 0, 0);
      acc[nt] = __builtin_amdgcn_mfma_f32_16x16x32_bf16(afr[2], b2, acc[nt], 0, 0, 0);
      acc[nt] = __builtin_amdgcn_mfma_f32_16x16x32_bf16(afr[3], b3, acc[nt], 0, 0, 0);
    }
  }

#pragma unroll
  for (int r = 0; r < 4; ++r) {
    int rowD = m0 + wv * 16 + quad * 4 + r;
    float p = 0.f, q = 0.f, s1 = 0.f;
#pragma unroll
    for (int nt = 0; nt < 8; ++nt) {
      float v = acc[nt][r] + bias_c[nt];
      float e = (v > 0.f) ? v : (expf(v) - 1.f);
      p += e; q += e * e; s1 += e * gw[nt];
    }
#pragma unroll
    for (int m = 8; m >= 1; m >>= 1) {
      p += __shfl_xor(p, m, 64);
      q += __shfl_xor(q, m, 64);
      s1 += __shfl_xor(s1, m, 64);
    }
    if (ln15 == 0 && rowD < M) {
      float mean = p * (1.0f / HD);
      float var = q * (1.0f / HD) - mean * mean;
      float rstd = rsqrtf(var + 1e-5f);
      float o = rstd * (s1 - mean * pg) + pb;
      atomicAdd(&accb[batch[rowD]], o);
    }
  }
}

__global__ void final_kernel(const float* __restrict__ accb, const float* __restrict__ pcnt,
                             const float* __restrict__ bl, float* __restrict__ out) {
  int b = blockIdx.x * 256 + threadIdx.x;
  if (b < NB) out[b] = accb[b] / fmaxf(pcnt[b], 1.0f) + bl[0];
}

// =================== host ===================
extern "C" void kernel_launch(void* const* d_in, const int* in_sizes, int n_in,
                              void* d_out, int out_size, void* d_ws, size_t ws_size,
                              hipStream_t stream) {
  const float* xt[7];
  for (int t = 0; t < 7; ++t) xt[t] = (const float*)d_in[t];
  const int* ei[14];
  for (int r = 0; r < 14; ++r) ei[r] = (const int*)d_in[7 + r];
  const int* batch = (const int*)d_in[21];
  const float* Wemb[7]; const float* bemb[7];
  for (int t = 0; t < 7; ++t) { Wemb[t] = (const float*)d_in[22 + 2 * t]; bemb[t] = (const float*)d_in[23 + 2 * t]; }
  const float* c_root[2] = {(const float*)d_in[36], (const float*)d_in[39]};
  const float* c_rel[2]  = {(const float*)d_in[37], (const float*)d_in[40]};
  const float* c_bias[2] = {(const float*)d_in[38], (const float*)d_in[41]};
  const float* ng[2] = {(const float*)d_in[42], (const float*)d_in[44]};
  const float* nbv[2] = {(const float*)d_in[43], (const float*)d_in[45]};
  const float* Wlin = (const float*)d_in[46];
  const float* blin = (const float*)d_in[47];
  float* out = (float*)d_out;

  char* base = (char*)d_ws;
  size_t off = 0;
  auto alloc = [&](size_t bytes) -> void* {
    void* p = base + off;
    off += (bytes + 255) & ~(size_t)255;
    return p;
  };
  __hip_bfloat16* Hb = (__hip_bfloat16*)alloc((size_t)N_L1 * HD * 2);
  float* AGR  = (float*)alloc((size_t)AGR_TOT * 4);
  // contiguous zero region: ICNT | ACC | PCNT  (single memset)
  int*   ICNT = (int*)alloc((size_t)CNT_TOT * 4 + (size_t)2 * NB * 4);
  float* ACC  = (float*)(ICNT + CNT_TOT);
  float* PCNT = ACC + NB;
  int*   CUR  = (int*)alloc((size_t)CNT_TOT * 4);
  int2*  OFF2 = (int2*)alloc((size_t)CNT_TOT * 8);
  int*   EDG  = (int*)alloc((size_t)EDG_TOT * 4);
  int*   BS   = (int*)alloc((size_t)1152 * 4);
  float* WL1  = (float*)alloc((size_t)WL1_ROWS * 128 * 4);
  __hip_bfloat16* WT3 = (__hip_bfloat16*)alloc((size_t)6 * 16384 * 2);

  static const int l1_rels[12] = {0,1,2,3,4,5,6,7,8,11,12,13};

  // ---- single memset: ICNT + ACC + PCNT ----
  hipMemsetAsync(ICNT, 0, (size_t)CNT_TOT * 4 + (size_t)2 * NB * 4, stream);

  // ---- prep: 12 edge-count jobs + batch counts + weights (one kernel) ----
  PrepPack PP;
  int blk = 0;
  for (int q = 0; q < 12; ++q) {
    int r = l1_rels[q];
    PP.j[q].dst = ei[r] + REL_E[r];
    PP.j[q].coff = CNT_OFF[r];
    PP.j[q].E = REL_E[r];
    PP.j[q].blk0 = blk;
    blk += (REL_E[r] + 255) / 256;
  }
  PP.bblk0 = blk; PP.batch = batch; PP.pcnt = PCNT; PP.nop = N_OP;
  blk += (N_OP + 255) / 256;
  PP.wstart = blk;
  for (int q = 0; q < 12; ++q) {
    int r = l1_rels[q]; int t = SRC_T[r];
    CombJob& J = PP.c[q];
    J.A = Wemb[t]; J.bin = bemb[t]; J.Mtx = c_rel[0] + (size_t)r * HD * HD;
    J.extra = nullptr;
    J.Wout = WL1 + (size_t)RELW[r] * 128;
    J.bout = WL1 + (size_t)RELI[r] * 128;
    J.F = TF[t];
  }
  for (int t = 0; t < 5; ++t) {
    CombJob& J = PP.c[12 + t];
    J.A = Wemb[t]; J.bin = bemb[t]; J.Mtx = c_root[0];
    J.extra = c_bias[0];
    J.Wout = WL1 + (size_t)ROOTW[t] * 128;
    J.bout = WL1 + (size_t)ROOTB[t] * 128;
    J.F = TF[t];
  }
  prep_k<<<blk + 23, 256, 0, stream>>>(PP, c_root[1], c_rel[1], WT3, ICNT);

  // ---- scan: local prefix + per-block base-by-reduction ----
  int nb1 = (CNT_TOT + SCAN_BLK - 1) / SCAN_BLK;   // 1133
  scan1<<<nb1, 256, 0, stream>>>(ICNT, CUR, BS, CNT_TOT);
  scan3b<<<nb1, 256, 0, stream>>>(CUR, OFF2, ICNT, BS, CNT_TOT);

  // ---- fill CSR ----
  FPackK FP;
  blk = 0;
  for (int q = 0; q < 12; ++q) {
    int r = l1_rels[q];
    FP.j[q].src = ei[r];
    FP.j[q].dst = ei[r] + REL_E[r];
    FP.j[q].coff = CNT_OFF[r];
    FP.j[q].E = REL_E[r];
    FP.j[q].blk0 = blk;
    blk += (REL_E[r] + 255) / 256;
  }
  fill_k<<<blk, 256, 0, stream>>>(FP, CUR, EDG);

  // ---- gather: one thread per (rel,dst), writes pre-averaged AGR ----
  GPack GP;
  blk = 0;
  for (int q = 0; q < 12; ++q) {
    int r = l1_rels[q]; int t = SRC_T[r];
    GP.j[q].x = xt[t];
    GP.j[q].agr = AGR + AGR_OFF[r];
    GP.j[q].coff = CNT_OFF[r];
    GP.j[q].D = REL_DSZ[r];
    GP.j[q].F = TF[t];
    GP.j[q].blk0 = blk;
    blk += (REL_DSZ[r] + 255) / 256;
  }
  gather_all<<<blk, 256, 0, stream>>>(GP, OFF2, EDG);

  // ---- layer 1: 4 rows/wave, vectorized s-loads ----
  L1v2 A;
  A.x0 = xt[0]; A.x1 = xt[1]; A.x2 = xt[2]; A.x3 = xt[3]; A.x4 = xt[4];
  A.AGR = AGR; A.WL1 = WL1; A.OFF2 = OFF2;
  A.g = ng[0]; A.b = nbv[0]; A.Hb = (unsigned short*)Hb;
  layer1_v5<<<6252, 256, 0, stream>>>(A);

  // ---- layer 2: barrier-free, 64 rows/block, register B-fragments ----
  l2_fused<<<(N_OP + 63) / 64, 256, 0, stream>>>(
      (const unsigned short*)Hb, (const unsigned short*)WT3,
      OFF2, EDG, c_bias[1], ng[1], nbv[1], Wlin, batch, ACC, N_OP);

  // ---- final scale ----
  final_kernel<<<(NB + 255) / 256, 256, 0, stream>>>(ACC, PCNT, blin, out);
}

// Round 15
// 600.395 us; speedup vs baseline: 1.4614x; 1.0042x over previous
//
#include <hip/hip_runtime.h>
#include <hip/hip_bf16.h>
#include <math.h>

#define HD 128
#define N_OP 100000
#define N_L1 400000
#define NB 2048
#define CNT_TOT 1160000
#define EDG_TOT 1100000

typedef short short8 __attribute__((ext_vector_type(8)));
typedef float floatx4 __attribute__((ext_vector_type(4)));

// relation tables (from reference EDGES/OFFS)
static const int REL_E[14]    = {100000,100000,100000,100000,100000,100000,100000,100000,100000,50000,50000,20000,120000,60000};
static const int REL_DSZ[14]  = {100000,100000,100000,100000,100000,100000,60000,100000,100000,50000,50000,20000,120000,60000};
static const int CNT_OFF[14]  = {0,100000,200000,300000,400000,500000,600000,660000,760000,860000,910000,960000,980000,1100000};
static const int SRC_T[14] = {1,3,2,2,0,4,4,5,6,5,6,1,2,3};
static const int TF[7]  = {4,2,10,4,8,1,1};
static const size_t AGR_OFF[14] = {0,200000,600000,1600000,2600000,3000000,3800000,4280000,4380000,0,0,4480000,4520000,5720000};
#define AGR_TOT 5960000
// WL1 packed blob row offsets (rows of 128 floats); bias row last per type
static const int RELW[14] = {4,7,12,93,23,28,70,104,106,-1,-1,40,54,79};
static const int RELI[14] = {6,11,22,103,27,36,78,105,107,-1,-1,42,64,83};
static const int ROOTW[5] = {0,38,44,66,85};
static const int ROOTB[5] = {37,43,65,84,108};
#define WL1_ROWS 109

// ---------------- bf16 helpers ----------------
__device__ inline unsigned short f2bf(float f) {
  union { float f; unsigned int u; } v; v.f = f;
  unsigned int r = v.u + 0x7FFF + ((v.u >> 16) & 1);
  return (unsigned short)(r >> 16);
}
__device__ inline float bfu2f(unsigned short u) {
  union { unsigned int i; float f; } v; v.i = ((unsigned int)u) << 16; return v.f;
}

// ============ prep: 12 edge-count jobs + batch counts + 17 combine + 6 repack, ONE kernel ============
struct CJob { const int* dst; int coff; int E; int blk0; };
struct CombJob { const float* A; const float* bin; const float* Mtx; const float* extra; float* Wout; float* bout; int F; };
struct PrepPack {
  CJob j[12];
  int bblk0;      // first block of batch-count range
  int wstart;     // first block of weights range
  const int* batch; float* pcnt; int nop;
  CombJob c[17];
};

__global__ void prep_k(PrepPack P, const float* __restrict__ c2root,
                       const float* __restrict__ c2rel, __hip_bfloat16* __restrict__ Wt,
                       int* __restrict__ ICNT) {
  int b = blockIdx.x;
  if (b >= P.wstart) {
    int wj = b - P.wstart;
    if (wj < 17) {
      if (threadIdx.x >= 128) return;
      CombJob J = P.c[wj];
      int c = threadIdx.x;
      for (int f = 0; f <= J.F; ++f) {
        const float* arow = (f < J.F) ? &J.A[f * HD] : J.bin;
        float s = (f < J.F) ? 0.f : (J.extra ? J.extra[c] : 0.f);
        for (int k = 0; k < HD; ++k) s = fmaf(arow[k], J.Mtx[k * HD + c], s);
        if (f < J.F) J.Wout[f * HD + c] = s;
        else J.bout[c] = s;
      }
    } else {
      const int RID[6] = {-1, 0, 1, 2, 4, 5};
      int j = wj - 17;
      const float* W = (j == 0) ? c2root : (c2rel + (size_t)RID[j] * HD * HD);
      __hip_bfloat16* o = Wt + (size_t)j * 16384;
      for (int i = threadIdx.x; i < 16384; i += 256) {
        int i8 = i & 7;
        int ln = (i >> 3) & 63;
        int k4 = (i >> 9) & 3;
        int nt = i >> 11;
        int ln15 = ln & 15, quad = ln >> 4;
        int k = k4 * 32 + quad * 8 + i8;
        int n = nt * 16 + ln15;
        o[i] = __float2bfloat16(W[k * 128 + n]);
      }
    }
    return;
  }
  if (b >= P.bblk0) {
    int i = (b - P.bblk0) * 256 + threadIdx.x;
    if (i < P.nop) atomicAdd(&P.pcnt[P.batch[i]], 1.0f);
    return;
  }
  int ji = 0;
#pragma unroll
  for (int i = 1; i < 12; ++i) if (b >= P.j[i].blk0) ji = i;
  CJob J = P.j[ji];
  int e = (b - J.blk0) * 256 + threadIdx.x;
  if (e < J.E) atomicAdd(&ICNT[J.coff + J.dst[e]], 1);
}

// ============ scans ============
#define SCAN_BLK 1024
__global__ void scan1(const int* __restrict__ in, int* __restrict__ out,
                      int* __restrict__ bsum, int n) {
  __shared__ int sh[256];
  int t = threadIdx.x;
  int base = blockIdx.x * SCAN_BLK + t * 4;
  int v0 = 0, v1 = 0, v2 = 0, v3 = 0;
  if (base + 3 < n) { int4 q = *(const int4*)&in[base]; v0 = q.x; v1 = q.y; v2 = q.z; v3 = q.w; }
  else {
    if (base < n) v0 = in[base];
    if (base + 1 < n) v1 = in[base + 1];
    if (base + 2 < n) v2 = in[base + 2];
    if (base + 3 < n) v3 = in[base + 3];
  }
  int ts = v0 + v1 + v2 + v3;
  sh[t] = ts; __syncthreads();
  for (int o = 1; o < 256; o <<= 1) {
    int x = (t >= o) ? sh[t - o] : 0;
    __syncthreads();
    sh[t] += x;
    __syncthreads();
  }
  int excl = sh[t] - ts;
  if (base < n) out[base] = excl;
  if (base + 1 < n) out[base + 1] = excl + v0;
  if (base + 2 < n) out[base + 2] = excl + v0 + v1;
  if (base + 3 < n) out[base + 3] = excl + v0 + v1 + v2;
  if (t == 255) bsum[blockIdx.x] = sh[255];
}

// per-1024-entry block: base = SUM(bs[0..j-1]) via parallel reduction
__global__ void scan3b(int* __restrict__ CUR, int2* __restrict__ OFF2,
                       const int* __restrict__ ICNT, const int* __restrict__ bs, int n) {
  __shared__ int sh[4];
  const int j = blockIdx.x, t = threadIdx.x;
  int s = 0;
  for (int i = t; i < j; i += 256) s += bs[i];
#pragma unroll
  for (int m = 32; m >= 1; m >>= 1) s += __shfl_xor(s, m, 64);
  if ((t & 63) == 0) sh[t >> 6] = s;
  __syncthreads();
  int base = sh[0] + sh[1] + sh[2] + sh[3];
  int i0 = j * SCAN_BLK + t * 4;
#pragma unroll
  for (int k = 0; k < 4; ++k) {
    int i = i0 + k;
    if (i < n) {
      int o = CUR[i] + base;
      CUR[i] = o;
      OFF2[i] = make_int2(o, ICNT[i]);
    }
  }
}

// ============ fill: EDG[pos] = src, grouped by (rel,dst) ============
struct FJob { const int* src; const int* dst; int coff; int E; int blk0; };
struct FPackK { FJob j[12]; };

__global__ void fill_k(FPackK P, int* __restrict__ CUR, int* __restrict__ EDG) {
  int b = blockIdx.x;
  int ji = 0;
#pragma unroll
  for (int i = 1; i < 12; ++i) if (b >= P.j[i].blk0) ji = i;
  FJob J = P.j[ji];
  int e = (b - J.blk0) * 256 + threadIdx.x;
  if (e < J.E) {
    int pos = atomicAdd(&CUR[J.coff + J.dst[e]], 1);
    EDG[pos] = J.src[e];
  }
}

// ============ gather_all: one thread per (rel,dst), AGR[d,:F] = mean(x[src,:F]) ============
struct GJob { const float* x; float* agr; int coff; int D; int F; int blk0; };
struct GPack { GJob j[12]; };

template <int F>
__device__ inline void gathF(const float* __restrict__ x, float* __restrict__ agr,
                             const int* __restrict__ EDG, int2 oc, int d) {
  if (oc.y == 0) return;
  float s[F];
#pragma unroll
  for (int f = 0; f < F; ++f) s[f] = 0.f;
  for (int e = 0; e < oc.y; ++e) {
    int si = EDG[oc.x + e];
    const float* xp = &x[(size_t)si * F];
    if (F == 1) {
      s[0] += xp[0];
    } else if (F == 2) {
      float2 v = *(const float2*)xp; s[0] += v.x; s[1] += v.y;
    } else if (F == 4) {
      float4 v = *(const float4*)xp;
      s[0] += v.x; s[1] += v.y; s[2] += v.z; s[3] += v.w;
    } else if (F == 8) {
      float4 v0 = *(const float4*)xp, v1 = *(const float4*)(xp + 4);
      s[0] += v0.x; s[1] += v0.y; s[2] += v0.z; s[3] += v0.w;
      s[4] += v1.x; s[5] += v1.y; s[6] += v1.z; s[7] += v1.w;
    } else {
#pragma unroll
      for (int j = 0; j < F / 2; ++j) {
        float2 v = *(const float2*)(xp + 2 * j);
        s[2 * j] += v.x; s[2 * j + 1] += v.y;
      }
    }
  }
  float rc = 1.0f / (float)oc.y;
#pragma unroll
  for (int f = 0; f < F; ++f) s[f] *= rc;
  float* ap = &agr[(size_t)d * F];
  if (F == 1) { ap[0] = s[0]; }
  else if (F == 2) { *(float2*)ap = make_float2(s[0], s[1]); }
  else if (F == 4) { *(float4*)ap = make_float4(s[0], s[1], s[2], s[3]); }
  else if (F == 8) {
    *(float4*)ap = make_float4(s[0], s[1], s[2], s[3]);
    *(float4*)(ap + 4) = make_float4(s[4], s[5], s[6], s[7]);
  } else {
#pragma unroll
    for (int j = 0; j < F / 2; ++j)
      *(float2*)(ap + 2 * j) = make_float2(s[2 * j], s[2 * j + 1]);
  }
}

__global__ void gather_all(GPack P, const int2* __restrict__ OFF2, const int* __restrict__ EDG) {
  int b = blockIdx.x;
  int ji = 0;
#pragma unroll
  for (int i = 1; i < 12; ++i) if (b >= P.j[i].blk0) ji = i;
  GJob J = P.j[ji];
  int d = (b - J.blk0) * 256 + threadIdx.x;
  if (d >= J.D) return;
  int2 oc = OFF2[J.coff + d];
  switch (J.F) {
    case 1:  gathF<1>(J.x, J.agr, EDG, oc, d); break;
    case 2:  gathF<2>(J.x, J.agr, EDG, oc, d); break;
    case 4:  gathF<4>(J.x, J.agr, EDG, oc, d); break;
    case 8:  gathF<8>(J.x, J.agr, EDG, oc, d); break;
    default: gathF<10>(J.x, J.agr, EDG, oc, d); break;
  }
}

// ============ layer-1 v5: LDS weights, 4 rows/wave, vectorized s-loads ============
struct L1v2 {
  const float* x0; const float* x1; const float* x2; const float* x3; const float* x4;
  const float* AGR; const float* WL1; const int2* OFF2;
  const float* g; const float* b;
  unsigned short* Hb;
};

__device__ inline void ldv2(float* s, const float* __restrict__ p) {
  float2 v = *(const float2*)p; s[0] = v.x; s[1] = v.y;
}
__device__ inline void ldv4(float* s, const float* __restrict__ p) {
  float4 v = *(const float4*)p; s[0] = v.x; s[1] = v.y; s[2] = v.z; s[3] = v.w;
}
__device__ inline void relF1(float* s, const float* __restrict__ agr,
                             const int2* __restrict__ OFF2, int cb, int row) {
  if (OFF2[cb + row].y > 0) { s[0] = agr[row]; s[1] = 1.f; }
  else { s[0] = 0.f; s[1] = 0.f; }
}
__device__ inline void relF2(float* s, const float* __restrict__ agr,
                             const int2* __restrict__ OFF2, int cb, int row) {
  if (OFF2[cb + row].y > 0) { ldv2(s, &agr[(size_t)row * 2]); s[2] = 1.f; }
  else { s[0] = s[1] = s[2] = 0.f; }
}
__device__ inline void relF4(float* s, const float* __restrict__ agr,
                             const int2* __restrict__ OFF2, int cb, int row) {
  if (OFF2[cb + row].y > 0) { ldv4(s, &agr[(size_t)row * 4]); s[4] = 1.f; }
  else {
#pragma unroll
    for (int f = 0; f < 5; ++f) s[f] = 0.f;
  }
}
__device__ inline void relF8(float* s, const float* __restrict__ agr,
                             const int2* __restrict__ OFF2, int cb, int row) {
  if (OFF2[cb + row].y > 0) {
    ldv4(s, &agr[(size_t)row * 8]); ldv4(s + 4, &agr[(size_t)row * 8 + 4]); s[8] = 1.f;
  } else {
#pragma unroll
    for (int f = 0; f < 9; ++f) s[f] = 0.f;
  }
}
__device__ inline void relF10(float* s, const float* __restrict__ agr,
                              const int2* __restrict__ OFF2, int cb, int row) {
  if (OFF2[cb + row].y > 0) {
    const float* p = &agr[(size_t)row * 10];
#pragma unroll
    for (int j = 0; j < 5; ++j) ldv2(s + 2 * j, p + 2 * j);
    s[10] = 1.f;
  } else {
#pragma unroll
    for (int f = 0; f < 11; ++f) s[f] = 0.f;
  }
}

template <int KT>
__device__ inline void l1_dot8(const float* __restrict__ Ls, const float (&s)[KT],
                               int c4, float (&a)[8]) {
  {
    float4 w0 = *(const float4*)&Ls[KT * 128 + c4];
    float4 w1 = *(const float4*)&Ls[KT * 128 + c4 + 64];
    a[0] = w0.x; a[1] = w0.y; a[2] = w0.z; a[3] = w0.w;
    a[4] = w1.x; a[5] = w1.y; a[6] = w1.z; a[7] = w1.w;
  }
#pragma unroll
  for (int k = 0; k < KT; ++k) {
    float4 w0 = *(const float4*)&Ls[k * 128 + c4];
    float4 w1 = *(const float4*)&Ls[k * 128 + c4 + 64];
    a[0] = fmaf(s[k], w0.x, a[0]); a[1] = fmaf(s[k], w0.y, a[1]);
    a[2] = fmaf(s[k], w0.z, a[2]); a[3] = fmaf(s[k], w0.w, a[3]);
    a[4] = fmaf(s[k], w1.x, a[4]); a[5] = fmaf(s[k], w1.y, a[5]);
    a[6] = fmaf(s[k], w1.z, a[6]); a[7] = fmaf(s[k], w1.w, a[7]);
  }
}

__device__ inline void l1_fin8(float (&a)[8], int c4, const float* __restrict__ g,
                               const float* __restrict__ bb,
                               unsigned short* __restrict__ Hb, int orow) {
  float p = 0.f, q = 0.f;
#pragma unroll
  for (int j = 0; j < 8; ++j) {
    a[j] = (a[j] > 0.f) ? a[j] : (expf(a[j]) - 1.f);
    p += a[j]; q += a[j] * a[j];
  }
#pragma unroll
  for (int m = 8; m >= 1; m >>= 1) {
    p += __shfl_xor(p, m, 64);
    q += __shfl_xor(q, m, 64);
  }
  float mean = p * (1.0f / HD);
  float var = q * (1.0f / HD) - mean * mean;
  float rstd = rsqrtf(var + 1e-5f);
  float4 g0 = *(const float4*)&g[c4], g1 = *(const float4*)&g[c4 + 64];
  float4 b0 = *(const float4*)&bb[c4], b1 = *(const float4*)&bb[c4 + 64];
  float gg[8] = {g0.x, g0.y, g0.z, g0.w, g1.x, g1.y, g1.z, g1.w};
  float bv[8] = {b0.x, b0.y, b0.z, b0.w, b1.x, b1.y, b1.z, b1.w};
  float o[8];
#pragma unroll
  for (int j = 0; j < 8; ++j) o[j] = (a[j] - mean) * rstd * gg[j] + bv[j];
  uint2 lo, hi;
  lo.x = (unsigned int)f2bf(o[0]) | ((unsigned int)f2bf(o[1]) << 16);
  lo.y = (unsigned int)f2bf(o[2]) | ((unsigned int)f2bf(o[3]) << 16);
  hi.x = (unsigned int)f2bf(o[4]) | ((unsigned int)f2bf(o[5]) << 16);
  hi.y = (unsigned int)f2bf(o[6]) | ((unsigned int)f2bf(o[7]) << 16);
  *(uint2*)&Hb[(size_t)orow * HD + c4] = lo;
  *(uint2*)&Hb[(size_t)orow * HD + c4 + 64] = hi;
}

__global__ __launch_bounds__(256) void layer1_v5(L1v2 A) {
  __shared__ float Ls[38 * 128];
  const int b = blockIdx.x, t = threadIdx.x;
  const int wv = t >> 6, ln = t & 63;
  const int sub = ln >> 4, c4 = (ln & 15) * 4;
  int type, seg;
  if (b < 1563) { type = 0; seg = b; }
  else if (b < 1876) { type = 1; seg = b - 1563; }
  else if (b < 3751) { type = 2; seg = b - 1876; }
  else if (b < 4689) { type = 3; seg = b - 3751; }
  else { type = 4; seg = b - 4689; }
  const int NR[5] = {38, 6, 22, 19, 24};
  const int RB[5] = {0, 38, 44, 66, 85};
  const int TR[5] = {100000, 20000, 120000, 60000, 100000};
  const int OB[5] = {0, 100000, 120000, 240000, 300000};
  {
    const float4* src = (const float4*)(A.WL1 + RB[type] * 128);
    float4* dst = (float4*)Ls;
    int n4 = NR[type] * 32;
    for (int i = t; i < n4; i += 256) dst[i] = src[i];
  }
  __syncthreads();
  const int row0 = seg * 64, M = TR[type], ob = OB[type];

  if (type == 0) {
#pragma unroll
    for (int it = 0; it < 4; ++it) {
      int row = row0 + it * 16 + wv * 4 + sub;
      if (row >= M) continue;
      float s[37];
      ldv4(s, &A.x0[(size_t)row * 4]);
      relF2(s + 4, A.AGR + 0, A.OFF2, 0, row);
      relF4(s + 7, A.AGR + 200000, A.OFF2, 100000, row);
      relF10(s + 12, A.AGR + 600000, A.OFF2, 200000, row);
      relF4(s + 23, A.AGR + 2600000, A.OFF2, 400000, row);
      relF8(s + 28, A.AGR + 3000000, A.OFF2, 500000, row);
      float a[8];
      l1_dot8<37>(Ls, s, c4, a);
      l1_fin8(a, c4, A.g, A.b, A.Hb, ob + row);
    }
  } else if (type == 1) {
#pragma unroll
    for (int it = 0; it < 4; ++it) {
      int row = row0 + it * 16 + wv * 4 + sub;
      if (row >= M) continue;
      float s[5];
      ldv2(s, &A.x1[(size_t)row * 2]);
      relF2(s + 2, A.AGR + 4480000, A.OFF2, 960000, row);
      float a[8];
      l1_dot8<5>(Ls, s, c4, a);
      l1_fin8(a, c4, A.g, A.b, A.Hb, ob + row);
    }
  } else if (type == 2) {
#pragma unroll
    for (int it = 0; it < 4; ++it) {
      int row = row0 + it * 16 + wv * 4 + sub;
      if (row >= M) continue;
      float s[21];
      const float* p = &A.x2[(size_t)row * 10];
#pragma unroll
      for (int j = 0; j < 5; ++j) ldv2(s + 2 * j, p + 2 * j);
      relF10(s + 10, A.AGR + 4520000, A.OFF2, 980000, row);
      float a[8];
      l1_dot8<21>(Ls, s, c4, a);
      l1_fin8(a, c4, A.g, A.b, A.Hb, ob + row);
    }
  } else if (type == 3) {
#pragma unroll
    for (int it = 0; it < 4; ++it) {
      int row = row0 + it * 16 + wv * 4 + sub;
      if (row >= M) continue;
      float s[18];
      ldv4(s, &A.x3[(size_t)row * 4]);
      relF8(s + 4, A.AGR + 3800000, A.OFF2, 600000, row);
      relF4(s + 13, A.AGR + 5720000, A.OFF2, 1100000, row);
      float a[8];
      l1_dot8<18>(Ls, s, c4, a);
      l1_fin8(a, c4, A.g, A.b, A.Hb, ob + row);
    }
  } else {
#pragma unroll
    for (int it = 0; it < 4; ++it) {
      int row = row0 + it * 16 + wv * 4 + sub;
      if (row >= M) continue;
      float s[23];
      ldv4(s, &A.x4[(size_t)row * 8]);
      ldv4(s + 4, &A.x4[(size_t)row * 8 + 4]);
      relF10(s + 8, A.AGR + 1600000, A.OFF2, 300000, row);
      relF1(s + 19, A.AGR + 4280000, A.OFF2, 660000, row);
      relF1(s + 21, A.AGR + 4380000, A.OFF2, 760000, row);
      float a[8];
      l1_dot8<23>(Ls, s, c4, a);
      l1_fin8(a, c4, A.g, A.b, A.Hb, ob + row);
    }
  }
}

// ============ layer-2 v6: barrier-free + one-term-ahead row prefetch + deg-1 fast path ============
__global__ __launch_bounds__(256, 4)
void l2_fused(const unsigned short* __restrict__ Hb, const unsigned short* __restrict__ Wt,
              const int2* __restrict__ OFF2, const int* __restrict__ EDG,
              const float* __restrict__ c2bias, const float* __restrict__ n2g,
              const float* __restrict__ n2b, const float* __restrict__ Wl,
              const int* __restrict__ batch, float* __restrict__ accb, int M) {
  const int CSR_OFF[5] = {0, 100000, 200000, 400000, 500000};   // rels 0,1,2,4,5
  const int SOFF[5]    = {100000, 240000, 120000, 0, 300000};   // Hb row offset of src type
  const int t = threadIdx.x, wv = t >> 6, ln = t & 63;
  const int quad = ln >> 4, ln15 = ln & 15, q8 = quad * 8;
  const int m0 = blockIdx.x * 64;
  const int rowA = m0 + wv * 16 + ln15;

  // CSR descriptors + first-edge src (independent loads, in flight early)
  int2 ocs[5];
#pragma unroll
  for (int r = 0; r < 5; ++r)
    ocs[r] = (rowA < M) ? OFF2[CSR_OFF[r] + rowA] : make_int2(0, 0);
  int pre[5];
#pragma unroll
  for (int r = 0; r < 5; ++r)
    pre[r] = (ocs[r].y > 0) ? EDG[ocs[r].x] : 0;

  float bias_c[8], gw[8];
  float pg = 0.f, pb = 0.f;
#pragma unroll
  for (int nt = 0; nt < 8; ++nt) {
    int col = nt * 16 + ln15;
    float wl = Wl[col], gc = n2g[col], bc = n2b[col];
    bias_c[nt] = c2bias[col];
    gw[nt] = gc * wl;
    pg += gc * wl;
    pb += bc * wl;
  }
#pragma unroll
  for (int m = 8; m >= 1; m >>= 1) {
    pg += __shfl_xor(pg, m, 64);
    pb += __shfl_xor(pb, m, 64);
  }

  floatx4 acc[8];
#pragma unroll
  for (int b = 0; b < 8; ++b) acc[b] = (floatx4){0.f, 0.f, 0.f, 0.f};

  // prefetch root row into pipeline buffer
  short8 nbuf[4];
  if (rowA < M) {
#pragma unroll
    for (int k4 = 0; k4 < 4; ++k4)
      nbuf[k4] = *(const short8*)&Hb[(size_t)rowA * HD + k4 * 32 + q8];
  } else {
#pragma unroll
    for (int k4 = 0; k4 < 4; ++k4)
#pragma unroll
      for (int j = 0; j < 8; ++j) nbuf[k4][j] = 0;
  }

#pragma unroll
  for (int term = 0; term < 6; ++term) {
    // consume pipeline buffer
    short8 afr[4];
#pragma unroll
    for (int k4 = 0; k4 < 4; ++k4) afr[k4] = nbuf[k4];

    // issue next term's first-row prefetch BEFORE current term's work
    if (term < 5) {
      int2 ocn = ocs[term];
      if (ocn.y > 0) {
        size_t s = (size_t)(pre[term] + SOFF[term]);
#pragma unroll
        for (int k4 = 0; k4 < 4; ++k4)
          nbuf[k4] = *(const short8*)&Hb[s * HD + k4 * 32 + q8];
      } else {
#pragma unroll
        for (int k4 = 0; k4 < 4; ++k4)
#pragma unroll
          for (int j = 0; j < 8; ++j) nbuf[k4][j] = 0;
      }
    }

    // finalize afr: deg<=1 uses prefetched row directly (rc=1; bf16 round-trip exact)
    if (term > 0) {
      int2 oc = ocs[term - 1];
      if (oc.y > 1) {
        float sum[4][8];
#pragma unroll
        for (int k4 = 0; k4 < 4; ++k4)
#pragma unroll
          for (int j = 0; j < 8; ++j) sum[k4][j] = bfu2f((unsigned short)afr[k4][j]);
        int so = SOFF[term - 1];
        for (int e = 1; e < oc.y; ++e) {
          size_t s = (size_t)(EDG[oc.x + e] + so);
#pragma unroll
          for (int k4 = 0; k4 < 4; ++k4) {
            short8 h = *(const short8*)&Hb[s * HD + k4 * 32 + q8];
#pragma unroll
            for (int j = 0; j < 8; ++j) sum[k4][j] += bfu2f((unsigned short)h[j]);
          }
        }
        float rc = 1.0f / (float)oc.y;
#pragma unroll
        for (int k4 = 0; k4 < 4; ++k4)
#pragma unroll
          for (int j = 0; j < 8; ++j) afr[k4][j] = (short)f2bf(sum[k4][j] * rc);
      }
    }

    const unsigned short* wb = Wt + (size_t)term * 16384 + (size_t)ln * 8;
#pragma unroll
    for (int nt = 0; nt < 8; ++nt) {
      short8 b0 = *(const short8*)(wb + nt * 2048 + 0 * 512);
      short8 b1 = *(const short8*)(wb + nt * 2048 + 1 * 512);
      short8 b2 = *(const short8*)(wb + nt * 2048 + 2 * 512);
      short8 b3 = *(const short8*)(wb + nt * 2048 + 3 * 512);
      acc[nt] = __builtin_amdgcn_mfma_f32_16x16x32_bf16(afr[0], b0, acc[nt], 0, 0, 0);
      acc[nt] = __builtin_amdgcn_mfma_f32_16x16x32_bf16(afr[1], b1, acc[nt], 0, 0, 0);
      acc[nt] = __builtin_amdgcn_mfma_f32_16x16x32_bf16(afr[2], b2, acc[nt], 0, 0, 0);
      acc[nt] = __builtin_amdgcn_mfma_f32_16x16x32_bf16(afr[3], b3, acc[nt], 0, 0, 0);
    }
  }

  // fused epilogue: ELU + LN + dot(Wl) + batch pool
#pragma unroll
  for (int r = 0; r < 4; ++r) {
    int rowD = m0 + wv * 16 + quad * 4 + r;
    float p = 0.f, q = 0.f, s1 = 0.f;
#pragma unroll
    for (int nt = 0; nt < 8; ++nt) {
      float v = acc[nt][r] + bias_c[nt];
      float e = (v > 0.f) ? v : (expf(v) - 1.f);
      p += e; q += e * e; s1 += e * gw[nt];
    }
#pragma unroll
    for (int m = 8; m >= 1; m >>= 1) {
      p += __shfl_xor(p, m, 64);
      q += __shfl_xor(q, m, 64);
      s1 += __shfl_xor(s1, m, 64);
    }
    if (ln15 == 0 && rowD < M) {
      float mean = p * (1.0f / HD);
      float var = q * (1.0f / HD) - mean * mean;
      float rstd = rsqrtf(var + 1e-5f);
      float o = rstd * (s1 - mean * pg) + pb;
      atomicAdd(&accb[batch[rowD]], o);
    }
  }
}

__global__ void final_kernel(const float* __restrict__ accb, const float* __restrict__ pcnt,
                             const float* __restrict__ bl, float* __restrict__ out) {
  int b = blockIdx.x * 256 + threadIdx.x;
  if (b < NB) out[b] = accb[b] / fmaxf(pcnt[b], 1.0f) + bl[0];
}

// =================== host ===================
extern "C" void kernel_launch(void* const* d_in, const int* in_sizes, int n_in,
                              void* d_out, int out_size, void* d_ws, size_t ws_size,
                              hipStream_t stream) {
  const float* xt[7];
  for (int t = 0; t < 7; ++t) xt[t] = (const float*)d_in[t];
  const int* ei[14];
  for (int r = 0; r < 14; ++r) ei[r] = (const int*)d_in[7 + r];
  const int* batch = (const int*)d_in[21];
  const float* Wemb[7]; const float* bemb[7];
  for (int t = 0; t < 7; ++t) { Wemb[t] = (const float*)d_in[22 + 2 * t]; bemb[t] = (const float*)d_in[23 + 2 * t]; }
  const float* c_root[2] = {(const float*)d_in[36], (const float*)d_in[39]};
  const float* c_rel[2]  = {(const float*)d_in[37], (const float*)d_in[40]};
  const float* c_bias[2] = {(const float*)d_in[38], (const float*)d_in[41]};
  const float* ng[2] = {(const float*)d_in[42], (const float*)d_in[44]};
  const float* nbv[2] = {(const float*)d_in[43], (const float*)d_in[45]};
  const float* Wlin = (const float*)d_in[46];
  const float* blin = (const float*)d_in[47];
  float* out = (float*)d_out;

  char* base = (char*)d_ws;
  size_t off = 0;
  auto alloc = [&](size_t bytes) -> void* {
    void* p = base + off;
    off += (bytes + 255) & ~(size_t)255;
    return p;
  };
  __hip_bfloat16* Hb = (__hip_bfloat16*)alloc((size_t)N_L1 * HD * 2);
  float* AGR  = (float*)alloc((size_t)AGR_TOT * 4);
  // contiguous zero region: ICNT | ACC | PCNT  (single memset)
  int*   ICNT = (int*)alloc((size_t)CNT_TOT * 4 + (size_t)2 * NB * 4);
  float* ACC  = (float*)(ICNT + CNT_TOT);
  float* PCNT = ACC + NB;
  int*   CUR  = (int*)alloc((size_t)CNT_TOT * 4);
  int2*  OFF2 = (int2*)alloc((size_t)CNT_TOT * 8);
  int*   EDG  = (int*)alloc((size_t)EDG_TOT * 4);
  int*   BS   = (int*)alloc((size_t)1152 * 4);
  float* WL1  = (float*)alloc((size_t)WL1_ROWS * 128 * 4);
  __hip_bfloat16* WT3 = (__hip_bfloat16*)alloc((size_t)6 * 16384 * 2);

  static const int l1_rels[12] = {0,1,2,3,4,5,6,7,8,11,12,13};

  // ---- single memset: ICNT + ACC + PCNT ----
  hipMemsetAsync(ICNT, 0, (size_t)CNT_TOT * 4 + (size_t)2 * NB * 4, stream);

  // ---- prep: 12 edge-count jobs + batch counts + weights (one kernel) ----
  PrepPack PP;
  int blk = 0;
  for (int q = 0; q < 12; ++q) {
    int r = l1_rels[q];
    PP.j[q].dst = ei[r] + REL_E[r];
    PP.j[q].coff = CNT_OFF[r];
    PP.j[q].E = REL_E[r];
    PP.j[q].blk0 = blk;
    blk += (REL_E[r] + 255) / 256;
  }
  PP.bblk0 = blk; PP.batch = batch; PP.pcnt = PCNT; PP.nop = N_OP;
  blk += (N_OP + 255) / 256;
  PP.wstart = blk;
  for (int q = 0; q < 12; ++q) {
    int r = l1_rels[q]; int t = SRC_T[r];
    CombJob& J = PP.c[q];
    J.A = Wemb[t]; J.bin = bemb[t]; J.Mtx = c_rel[0] + (size_t)r * HD * HD;
    J.extra = nullptr;
    J.Wout = WL1 + (size_t)RELW[r] * 128;
    J.bout = WL1 + (size_t)RELI[r] * 128;
    J.F = TF[t];
  }
  for (int t = 0; t < 5; ++t) {
    CombJob& J = PP.c[12 + t];
    J.A = Wemb[t]; J.bin = bemb[t]; J.Mtx = c_root[0];
    J.extra = c_bias[0];
    J.Wout = WL1 + (size_t)ROOTW[t] * 128;
    J.bout = WL1 + (size_t)ROOTB[t] * 128;
    J.F = TF[t];
  }
  prep_k<<<blk + 23, 256, 0, stream>>>(PP, c_root[1], c_rel[1], WT3, ICNT);

  // ---- scan: local prefix + per-block base-by-reduction ----
  int nb1 = (CNT_TOT + SCAN_BLK - 1) / SCAN_BLK;   // 1133
  scan1<<<nb1, 256, 0, stream>>>(ICNT, CUR, BS, CNT_TOT);
  scan3b<<<nb1, 256, 0, stream>>>(CUR, OFF2, ICNT, BS, CNT_TOT);

  // ---- fill CSR ----
  FPackK FP;
  blk = 0;
  for (int q = 0; q < 12; ++q) {
    int r = l1_rels[q];
    FP.j[q].src = ei[r];
    FP.j[q].dst = ei[r] + REL_E[r];
    FP.j[q].coff = CNT_OFF[r];
    FP.j[q].E = REL_E[r];
    FP.j[q].blk0 = blk;
    blk += (REL_E[r] + 255) / 256;
  }
  fill_k<<<blk, 256, 0, stream>>>(FP, CUR, EDG);

  // ---- gather: one thread per (rel,dst), writes pre-averaged AGR ----
  GPack GP;
  blk = 0;
  for (int q = 0; q < 12; ++q) {
    int r = l1_rels[q]; int t = SRC_T[r];
    GP.j[q].x = xt[t];
    GP.j[q].agr = AGR + AGR_OFF[r];
    GP.j[q].coff = CNT_OFF[r];
    GP.j[q].D = REL_DSZ[r];
    GP.j[q].F = TF[t];
    GP.j[q].blk0 = blk;
    blk += (REL_DSZ[r] + 255) / 256;
  }
  gather_all<<<blk, 256, 0, stream>>>(GP, OFF2, EDG);

  // ---- layer 1: 4 rows/wave, vectorized s-loads ----
  L1v2 A;
  A.x0 = xt[0]; A.x1 = xt[1]; A.x2 = xt[2]; A.x3 = xt[3]; A.x4 = xt[4];
  A.AGR = AGR; A.WL1 = WL1; A.OFF2 = OFF2;
  A.g = ng[0]; A.b = nbv[0]; A.Hb = (unsigned short*)Hb;
  layer1_v5<<<6252, 256, 0, stream>>>(A);

  // ---- layer 2: barrier-free, pipelined row prefetch, deg-1 fast path ----
  l2_fused<<<(N_OP + 63) / 64, 256, 0, stream>>>(
      (const unsigned short*)Hb, (const unsigned short*)WT3,
      OFF2, EDG, c_bias[1], ng[1], nbv[1], Wlin, batch, ACC, N_OP);

  // ---- final scale ----
  final_kernel<<<(NB + 255) / 256, 256, 0, stream>>>(ACC, PCNT, blin, out);
}

// Round 16
// 598.937 us; speedup vs baseline: 1.4650x; 1.0024x over previous
//
#include <hip/hip_runtime.h>
#include <hip/hip_bf16.h>
#include <math.h>

#define HD 128
#define N_OP 100000
#define N_L1 400000
#define NB 2048
#define CNT_TOT 1160000
#define EDG_TOT 1100000

typedef short short8 __attribute__((ext_vector_type(8)));
typedef float floatx4 __attribute__((ext_vector_type(4)));

// relation tables (from reference EDGES/OFFS)
static const int REL_E[14]    = {100000,100000,100000,100000,100000,100000,100000,100000,100000,50000,50000,20000,120000,60000};
static const int REL_DSZ[14]  = {100000,100000,100000,100000,100000,100000,60000,100000,100000,50000,50000,20000,120000,60000};
static const int CNT_OFF[14]  = {0,100000,200000,300000,400000,500000,600000,660000,760000,860000,910000,960000,980000,1100000};
static const int SRC_T[14] = {1,3,2,2,0,4,4,5,6,5,6,1,2,3};
static const int TF[7]  = {4,2,10,4,8,1,1};
static const size_t AGR_OFF[14] = {0,200000,600000,1600000,2600000,3000000,3800000,4280000,4380000,0,0,4480000,4520000,5720000};
#define AGR_TOT 5960000
// WL1 packed blob row offsets (rows of 128 floats); bias row last per type
static const int RELW[14] = {4,7,12,93,23,28,70,104,106,-1,-1,40,54,79};
static const int RELI[14] = {6,11,22,103,27,36,78,105,107,-1,-1,42,64,83};
static const int ROOTW[5] = {0,38,44,66,85};
static const int ROOTB[5] = {37,43,65,84,108};
#define WL1_ROWS 109
// global edge-id base per job (l1_rels order: 0,1,2,3,4,5,6,7,8,11,12,13)
static const int EOFF12[12] = {0,100000,200000,300000,400000,500000,600000,700000,800000,900000,920000,1040000};

// ---------------- bf16 helpers ----------------
__device__ inline unsigned short f2bf(float f) {
  union { float f; unsigned int u; } v; v.f = f;
  unsigned int r = v.u + 0x7FFF + ((v.u >> 16) & 1);
  return (unsigned short)(r >> 16);
}
__device__ inline float bfu2f(unsigned short u) {
  union { unsigned int i; float f; } v; v.i = ((unsigned int)u) << 16; return v.f;
}

// ============ exch: linked-list adjacency build + batch counts + weights, ONE kernel ============
struct XJob { const int* src; const int* dst; int coff; int eoff; int E; int blk0; };
struct CombJob { const float* A; const float* bin; const float* Mtx; const float* extra; float* Wout; float* bout; int F; };
struct XPack {
  XJob j[12];
  int bblk0;      // first block of batch-count range
  int wstart;     // first block of weights range
  const int* batch; float* pcnt; int nop;
  CombJob c[17];
};

__global__ void exch_k(XPack P, const float* __restrict__ c2root,
                       const float* __restrict__ c2rel, __hip_bfloat16* __restrict__ Wt,
                       int* __restrict__ HEAD, int2* __restrict__ SRCNXT) {
  int b = blockIdx.x;
  if (b >= P.wstart) {
    int wj = b - P.wstart;
    if (wj < 17) {
      if (threadIdx.x >= 128) return;
      CombJob J = P.c[wj];
      int c = threadIdx.x;
      for (int f = 0; f <= J.F; ++f) {
        const float* arow = (f < J.F) ? &J.A[f * HD] : J.bin;
        float s = (f < J.F) ? 0.f : (J.extra ? J.extra[c] : 0.f);
        for (int k = 0; k < HD; ++k) s = fmaf(arow[k], J.Mtx[k * HD + c], s);
        if (f < J.F) J.Wout[f * HD + c] = s;
        else J.bout[c] = s;
      }
    } else {
      const int RID[6] = {-1, 0, 1, 2, 4, 5};
      int j = wj - 17;
      const float* W = (j == 0) ? c2root : (c2rel + (size_t)RID[j] * HD * HD);
      __hip_bfloat16* o = Wt + (size_t)j * 16384;
      for (int i = threadIdx.x; i < 16384; i += 256) {
        int i8 = i & 7;
        int ln = (i >> 3) & 63;
        int k4 = (i >> 9) & 3;
        int nt = i >> 11;
        int ln15 = ln & 15, quad = ln >> 4;
        int k = k4 * 32 + quad * 8 + i8;
        int n = nt * 16 + ln15;
        o[i] = __float2bfloat16(W[k * 128 + n]);
      }
    }
    return;
  }
  if (b >= P.bblk0) {
    int i = (b - P.bblk0) * 256 + threadIdx.x;
    if (i < P.nop) atomicAdd(&P.pcnt[P.batch[i]], 1.0f);
    return;
  }
  int ji = 0;
#pragma unroll
  for (int i = 1; i < 12; ++i) if (b >= P.j[i].blk0) ji = i;
  XJob J = P.j[ji];
  int e = (b - J.blk0) * 256 + threadIdx.x;
  if (e < J.E) {
    int d = J.dst[e];
    int ge = J.eoff + e;
    int old = atomicExch(&HEAD[J.coff + d], ge);
    SRCNXT[ge] = make_int2(J.src[e], old);   // coalesced 8B store
  }
}

// ============ gather_all: one thread per (rel,dst), list-traverse, AGR = mean(x[src,:F]) ============
struct GJob { const float* x; float* agr; int coff; int D; int F; int blk0; };
struct GPack { GJob j[12]; };

template <int F>
__device__ inline void gathF(const float* __restrict__ x, float* __restrict__ agr,
                             const int2* __restrict__ SRCNXT, int eg, int d) {
  float s[F];
#pragma unroll
  for (int f = 0; f < F; ++f) s[f] = 0.f;
  int n = 0;
  while (eg >= 0) {
    int2 sn = SRCNXT[eg];
    const float* xp = &x[(size_t)sn.x * F];
    if (F == 1) {
      s[0] += xp[0];
    } else if (F == 2) {
      float2 v = *(const float2*)xp; s[0] += v.x; s[1] += v.y;
    } else if (F == 4) {
      float4 v = *(const float4*)xp;
      s[0] += v.x; s[1] += v.y; s[2] += v.z; s[3] += v.w;
    } else if (F == 8) {
      float4 v0 = *(const float4*)xp, v1 = *(const float4*)(xp + 4);
      s[0] += v0.x; s[1] += v0.y; s[2] += v0.z; s[3] += v0.w;
      s[4] += v1.x; s[5] += v1.y; s[6] += v1.z; s[7] += v1.w;
    } else {
#pragma unroll
      for (int j = 0; j < F / 2; ++j) {
        float2 v = *(const float2*)(xp + 2 * j);
        s[2 * j] += v.x; s[2 * j + 1] += v.y;
      }
    }
    ++n;
    eg = sn.y;
  }
  float rc = 1.0f / (float)n;
#pragma unroll
  for (int f = 0; f < F; ++f) s[f] *= rc;
  float* ap = &agr[(size_t)d * F];
  if (F == 1) { ap[0] = s[0]; }
  else if (F == 2) { *(float2*)ap = make_float2(s[0], s[1]); }
  else if (F == 4) { *(float4*)ap = make_float4(s[0], s[1], s[2], s[3]); }
  else if (F == 8) {
    *(float4*)ap = make_float4(s[0], s[1], s[2], s[3]);
    *(float4*)(ap + 4) = make_float4(s[4], s[5], s[6], s[7]);
  } else {
#pragma unroll
    for (int j = 0; j < F / 2; ++j)
      *(float2*)(ap + 2 * j) = make_float2(s[2 * j], s[2 * j + 1]);
  }
}

__global__ void gather_all(GPack P, const int* __restrict__ HEAD,
                           const int2* __restrict__ SRCNXT) {
  int b = blockIdx.x;
  int ji = 0;
#pragma unroll
  for (int i = 1; i < 12; ++i) if (b >= P.j[i].blk0) ji = i;
  GJob J = P.j[ji];
  int d = (b - J.blk0) * 256 + threadIdx.x;
  if (d >= J.D) return;
  int eg = HEAD[J.coff + d];
  if (eg < 0) return;
  switch (J.F) {
    case 1:  gathF<1>(J.x, J.agr, SRCNXT, eg, d); break;
    case 2:  gathF<2>(J.x, J.agr, SRCNXT, eg, d); break;
    case 4:  gathF<4>(J.x, J.agr, SRCNXT, eg, d); break;
    case 8:  gathF<8>(J.x, J.agr, SRCNXT, eg, d); break;
    default: gathF<10>(J.x, J.agr, SRCNXT, eg, d); break;
  }
}

// ============ layer-1 v5: LDS weights, 4 rows/wave, vectorized s-loads ============
struct L1v2 {
  const float* x0; const float* x1; const float* x2; const float* x3; const float* x4;
  const float* AGR; const float* WL1; const int* HEAD;
  const float* g; const float* b;
  unsigned short* Hb;
};

__device__ inline void ldv2(float* s, const float* __restrict__ p) {
  float2 v = *(const float2*)p; s[0] = v.x; s[1] = v.y;
}
__device__ inline void ldv4(float* s, const float* __restrict__ p) {
  float4 v = *(const float4*)p; s[0] = v.x; s[1] = v.y; s[2] = v.z; s[3] = v.w;
}
__device__ inline void relF1(float* s, const float* __restrict__ agr,
                             const int* __restrict__ HEAD, int cb, int row) {
  if (HEAD[cb + row] >= 0) { s[0] = agr[row]; s[1] = 1.f; }
  else { s[0] = 0.f; s[1] = 0.f; }
}
__device__ inline void relF2(float* s, const float* __restrict__ agr,
                             const int* __restrict__ HEAD, int cb, int row) {
  if (HEAD[cb + row] >= 0) { ldv2(s, &agr[(size_t)row * 2]); s[2] = 1.f; }
  else { s[0] = s[1] = s[2] = 0.f; }
}
__device__ inline void relF4(float* s, const float* __restrict__ agr,
                             const int* __restrict__ HEAD, int cb, int row) {
  if (HEAD[cb + row] >= 0) { ldv4(s, &agr[(size_t)row * 4]); s[4] = 1.f; }
  else {
#pragma unroll
    for (int f = 0; f < 5; ++f) s[f] = 0.f;
  }
}
__device__ inline void relF8(float* s, const float* __restrict__ agr,
                             const int* __restrict__ HEAD, int cb, int row) {
  if (HEAD[cb + row] >= 0) {
    ldv4(s, &agr[(size_t)row * 8]); ldv4(s + 4, &agr[(size_t)row * 8 + 4]); s[8] = 1.f;
  } else {
#pragma unroll
    for (int f = 0; f < 9; ++f) s[f] = 0.f;
  }
}
__device__ inline void relF10(float* s, const float* __restrict__ agr,
                              const int* __restrict__ HEAD, int cb, int row) {
  if (HEAD[cb + row] >= 0) {
    const float* p = &agr[(size_t)row * 10];
#pragma unroll
    for (int j = 0; j < 5; ++j) ldv2(s + 2 * j, p + 2 * j);
    s[10] = 1.f;
  } else {
#pragma unroll
    for (int f = 0; f < 11; ++f) s[f] = 0.f;
  }
}

template <int KT>
__device__ inline void l1_dot8(const float* __restrict__ Ls, const float (&s)[KT],
                               int c4, float (&a)[8]) {
  {
    float4 w0 = *(const float4*)&Ls[KT * 128 + c4];
    float4 w1 = *(const float4*)&Ls[KT * 128 + c4 + 64];
    a[0] = w0.x; a[1] = w0.y; a[2] = w0.z; a[3] = w0.w;
    a[4] = w1.x; a[5] = w1.y; a[6] = w1.z; a[7] = w1.w;
  }
#pragma unroll
  for (int k = 0; k < KT; ++k) {
    float4 w0 = *(const float4*)&Ls[k * 128 + c4];
    float4 w1 = *(const float4*)&Ls[k * 128 + c4 + 64];
    a[0] = fmaf(s[k], w0.x, a[0]); a[1] = fmaf(s[k], w0.y, a[1]);
    a[2] = fmaf(s[k], w0.z, a[2]); a[3] = fmaf(s[k], w0.w, a[3]);
    a[4] = fmaf(s[k], w1.x, a[4]); a[5] = fmaf(s[k], w1.y, a[5]);
    a[6] = fmaf(s[k], w1.z, a[6]); a[7] = fmaf(s[k], w1.w, a[7]);
  }
}

__device__ inline void l1_fin8(float (&a)[8], int c4, const float* __restrict__ g,
                               const float* __restrict__ bb,
                               unsigned short* __restrict__ Hb, int orow) {
  float p = 0.f, q = 0.f;
#pragma unroll
  for (int j = 0; j < 8; ++j) {
    a[j] = (a[j] > 0.f) ? a[j] : (expf(a[j]) - 1.f);
    p += a[j]; q += a[j] * a[j];
  }
#pragma unroll
  for (int m = 8; m >= 1; m >>= 1) {
    p += __shfl_xor(p, m, 64);
    q += __shfl_xor(q, m, 64);
  }
  float mean = p * (1.0f / HD);
  float var = q * (1.0f / HD) - mean * mean;
  float rstd = rsqrtf(var + 1e-5f);
  float4 g0 = *(const float4*)&g[c4], g1 = *(const float4*)&g[c4 + 64];
  float4 b0 = *(const float4*)&bb[c4], b1 = *(const float4*)&bb[c4 + 64];
  float gg[8] = {g0.x, g0.y, g0.z, g0.w, g1.x, g1.y, g1.z, g1.w};
  float bv[8] = {b0.x, b0.y, b0.z, b0.w, b1.x, b1.y, b1.z, b1.w};
  float o[8];
#pragma unroll
  for (int j = 0; j < 8; ++j) o[j] = (a[j] - mean) * rstd * gg[j] + bv[j];
  uint2 lo, hi;
  lo.x = (unsigned int)f2bf(o[0]) | ((unsigned int)f2bf(o[1]) << 16);
  lo.y = (unsigned int)f2bf(o[2]) | ((unsigned int)f2bf(o[3]) << 16);
  hi.x = (unsigned int)f2bf(o[4]) | ((unsigned int)f2bf(o[5]) << 16);
  hi.y = (unsigned int)f2bf(o[6]) | ((unsigned int)f2bf(o[7]) << 16);
  *(uint2*)&Hb[(size_t)orow * HD + c4] = lo;
  *(uint2*)&Hb[(size_t)orow * HD + c4 + 64] = hi;
}

__global__ __launch_bounds__(256) void layer1_v5(L1v2 A) {
  __shared__ float Ls[38 * 128];
  const int b = blockIdx.x, t = threadIdx.x;
  const int wv = t >> 6, ln = t & 63;
  const int sub = ln >> 4, c4 = (ln & 15) * 4;
  int type, seg;
  if (b < 1563) { type = 0; seg = b; }
  else if (b < 1876) { type = 1; seg = b - 1563; }
  else if (b < 3751) { type = 2; seg = b - 1876; }
  else if (b < 4689) { type = 3; seg = b - 3751; }
  else { type = 4; seg = b - 4689; }
  const int NR[5] = {38, 6, 22, 19, 24};
  const int RB[5] = {0, 38, 44, 66, 85};
  const int TR[5] = {100000, 20000, 120000, 60000, 100000};
  const int OB[5] = {0, 100000, 120000, 240000, 300000};
  {
    const float4* src = (const float4*)(A.WL1 + RB[type] * 128);
    float4* dst = (float4*)Ls;
    int n4 = NR[type] * 32;
    for (int i = t; i < n4; i += 256) dst[i] = src[i];
  }
  __syncthreads();
  const int row0 = seg * 64, M = TR[type], ob = OB[type];

  if (type == 0) {
#pragma unroll
    for (int it = 0; it < 4; ++it) {
      int row = row0 + it * 16 + wv * 4 + sub;
      if (row >= M) continue;
      float s[37];
      ldv4(s, &A.x0[(size_t)row * 4]);
      relF2(s + 4, A.AGR + 0, A.HEAD, 0, row);
      relF4(s + 7, A.AGR + 200000, A.HEAD, 100000, row);
      relF10(s + 12, A.AGR + 600000, A.HEAD, 200000, row);
      relF4(s + 23, A.AGR + 2600000, A.HEAD, 400000, row);
      relF8(s + 28, A.AGR + 3000000, A.HEAD, 500000, row);
      float a[8];
      l1_dot8<37>(Ls, s, c4, a);
      l1_fin8(a, c4, A.g, A.b, A.Hb, ob + row);
    }
  } else if (type == 1) {
#pragma unroll
    for (int it = 0; it < 4; ++it) {
      int row = row0 + it * 16 + wv * 4 + sub;
      if (row >= M) continue;
      float s[5];
      ldv2(s, &A.x1[(size_t)row * 2]);
      relF2(s + 2, A.AGR + 4480000, A.HEAD, 960000, row);
      float a[8];
      l1_dot8<5>(Ls, s, c4, a);
      l1_fin8(a, c4, A.g, A.b, A.Hb, ob + row);
    }
  } else if (type == 2) {
#pragma unroll
    for (int it = 0; it < 4; ++it) {
      int row = row0 + it * 16 + wv * 4 + sub;
      if (row >= M) continue;
      float s[21];
      const float* p = &A.x2[(size_t)row * 10];
#pragma unroll
      for (int j = 0; j < 5; ++j) ldv2(s + 2 * j, p + 2 * j);
      relF10(s + 10, A.AGR + 4520000, A.HEAD, 980000, row);
      float a[8];
      l1_dot8<21>(Ls, s, c4, a);
      l1_fin8(a, c4, A.g, A.b, A.Hb, ob + row);
    }
  } else if (type == 3) {
#pragma unroll
    for (int it = 0; it < 4; ++it) {
      int row = row0 + it * 16 + wv * 4 + sub;
      if (row >= M) continue;
      float s[18];
      ldv4(s, &A.x3[(size_t)row * 4]);
      relF8(s + 4, A.AGR + 3800000, A.HEAD, 600000, row);
      relF4(s + 13, A.AGR + 5720000, A.HEAD, 1100000, row);
      float a[8];
      l1_dot8<18>(Ls, s, c4, a);
      l1_fin8(a, c4, A.g, A.b, A.Hb, ob + row);
    }
  } else {
#pragma unroll
    for (int it = 0; it < 4; ++it) {
      int row = row0 + it * 16 + wv * 4 + sub;
      if (row >= M) continue;
      float s[23];
      ldv4(s, &A.x4[(size_t)row * 8]);
      ldv4(s + 4, &A.x4[(size_t)row * 8 + 4]);
      relF10(s + 8, A.AGR + 1600000, A.HEAD, 300000, row);
      relF1(s + 19, A.AGR + 4280000, A.HEAD, 660000, row);
      relF1(s + 21, A.AGR + 4380000, A.HEAD, 760000, row);
      float a[8];
      l1_dot8<23>(Ls, s, c4, a);
      l1_fin8(a, c4, A.g, A.b, A.Hb, ob + row);
    }
  }
}

// ============ layer-2 v7: barrier-free, linked-list gather, pipelined prefetch + deg-1 fast path ============
__global__ __launch_bounds__(256, 4)
void l2_fused(const unsigned short* __restrict__ Hb, const unsigned short* __restrict__ Wt,
              const int* __restrict__ HEAD, const int2* __restrict__ SRCNXT,
              const float* __restrict__ c2bias, const float* __restrict__ n2g,
              const float* __restrict__ n2b, const float* __restrict__ Wl,
              const int* __restrict__ batch, float* __restrict__ accb, int M) {
  const int CSR_OFF[5] = {0, 100000, 200000, 400000, 500000};   // HEAD offsets of rels 0,1,2,4,5
  const int SOFF[5]    = {100000, 240000, 120000, 0, 300000};   // Hb row offset of src type
  const int t = threadIdx.x, wv = t >> 6, ln = t & 63;
  const int quad = ln >> 4, ln15 = ln & 15, q8 = quad * 8;
  const int m0 = blockIdx.x * 64;
  const int rowA = m0 + wv * 16 + ln15;

  // heads (independent) then first nodes (independent)
  int hd[5];
#pragma unroll
  for (int r = 0; r < 5; ++r)
    hd[r] = (rowA < M) ? HEAD[CSR_OFF[r] + rowA] : -1;
  int2 sn[5];
#pragma unroll
  for (int r = 0; r < 5; ++r)
    sn[r] = (hd[r] >= 0) ? SRCNXT[hd[r]] : make_int2(0, -1);

  float bias_c[8], gw[8];
  float pg = 0.f, pb = 0.f;
#pragma unroll
  for (int nt = 0; nt < 8; ++nt) {
    int col = nt * 16 + ln15;
    float wl = Wl[col], gc = n2g[col], bc = n2b[col];
    bias_c[nt] = c2bias[col];
    gw[nt] = gc * wl;
    pg += gc * wl;
    pb += bc * wl;
  }
#pragma unroll
  for (int m = 8; m >= 1; m >>= 1) {
    pg += __shfl_xor(pg, m, 64);
    pb += __shfl_xor(pb, m, 64);
  }

  floatx4 acc[8];
#pragma unroll
  for (int b = 0; b < 8; ++b) acc[b] = (floatx4){0.f, 0.f, 0.f, 0.f};

  // prefetch root row into pipeline buffer
  short8 nbuf[4];
  if (rowA < M) {
#pragma unroll
    for (int k4 = 0; k4 < 4; ++k4)
      nbuf[k4] = *(const short8*)&Hb[(size_t)rowA * HD + k4 * 32 + q8];
  } else {
#pragma unroll
    for (int k4 = 0; k4 < 4; ++k4)
#pragma unroll
      for (int j = 0; j < 8; ++j) nbuf[k4][j] = 0;
  }

#pragma unroll
  for (int term = 0; term < 6; ++term) {
    short8 afr[4];
#pragma unroll
    for (int k4 = 0; k4 < 4; ++k4) afr[k4] = nbuf[k4];

    // issue next term's first-row prefetch BEFORE current term's work
    if (term < 5) {
      if (hd[term] >= 0) {
        size_t s = (size_t)(sn[term].x + SOFF[term]);
#pragma unroll
        for (int k4 = 0; k4 < 4; ++k4)
          nbuf[k4] = *(const short8*)&Hb[s * HD + k4 * 32 + q8];
      } else {
#pragma unroll
        for (int k4 = 0; k4 < 4; ++k4)
#pragma unroll
          for (int j = 0; j < 8; ++j) nbuf[k4][j] = 0;
      }
    }

    // finalize afr: deg<=1 uses prefetched row directly (rc=1 exact)
    if (term > 0) {
      int r = term - 1;
      if (hd[r] >= 0 && sn[r].y >= 0) {   // degree >= 2: slow path
        float sum[4][8];
#pragma unroll
        for (int k4 = 0; k4 < 4; ++k4)
#pragma unroll
          for (int j = 0; j < 8; ++j) sum[k4][j] = bfu2f((unsigned short)afr[k4][j]);
        int so = SOFF[r];
        int n = 1;
        int eg = sn[r].y;
        while (eg >= 0) {
          int2 s2 = SRCNXT[eg];
          size_t s = (size_t)(s2.x + so);
#pragma unroll
          for (int k4 = 0; k4 < 4; ++k4) {
            short8 h = *(const short8*)&Hb[s * HD + k4 * 32 + q8];
#pragma unroll
            for (int j = 0; j < 8; ++j) sum[k4][j] += bfu2f((unsigned short)h[j]);
          }
          ++n;
          eg = s2.y;
        }
        float rc = 1.0f / (float)n;
#pragma unroll
        for (int k4 = 0; k4 < 4; ++k4)
#pragma unroll
          for (int j = 0; j < 8; ++j) afr[k4][j] = (short)f2bf(sum[k4][j] * rc);
      }
    }

    const unsigned short* wb = Wt + (size_t)term * 16384 + (size_t)ln * 8;
#pragma unroll
    for (int nt = 0; nt < 8; ++nt) {
      short8 b0 = *(const short8*)(wb + nt * 2048 + 0 * 512);
      short8 b1 = *(const short8*)(wb + nt * 2048 + 1 * 512);
      short8 b2 = *(const short8*)(wb + nt * 2048 + 2 * 512);
      short8 b3 = *(const short8*)(wb + nt * 2048 + 3 * 512);
      acc[nt] = __builtin_amdgcn_mfma_f32_16x16x32_bf16(afr[0], b0, acc[nt], 0, 0, 0);
      acc[nt] = __builtin_amdgcn_mfma_f32_16x16x32_bf16(afr[1], b1, acc[nt], 0, 0, 0);
      acc[nt] = __builtin_amdgcn_mfma_f32_16x16x32_bf16(afr[2], b2, acc[nt], 0, 0, 0);
      acc[nt] = __builtin_amdgcn_mfma_f32_16x16x32_bf16(afr[3], b3, acc[nt], 0, 0, 0);
    }
  }

  // fused epilogue: ELU + LN + dot(Wl) + batch pool
#pragma unroll
  for (int r = 0; r < 4; ++r) {
    int rowD = m0 + wv * 16 + quad * 4 + r;
    float p = 0.f, q = 0.f, s1 = 0.f;
#pragma unroll
    for (int nt = 0; nt < 8; ++nt) {
      float v = acc[nt][r] + bias_c[nt];
      float e = (v > 0.f) ? v : (expf(v) - 1.f);
      p += e; q += e * e; s1 += e * gw[nt];
    }
#pragma unroll
    for (int m = 8; m >= 1; m >>= 1) {
      p += __shfl_xor(p, m, 64);
      q += __shfl_xor(q, m, 64);
      s1 += __shfl_xor(s1, m, 64);
    }
    if (ln15 == 0 && rowD < M) {
      float mean = p * (1.0f / HD);
      float var = q * (1.0f / HD) - mean * mean;
      float rstd = rsqrtf(var + 1e-5f);
      float o = rstd * (s1 - mean * pg) + pb;
      atomicAdd(&accb[batch[rowD]], o);
    }
  }
}

__global__ void final_kernel(const float* __restrict__ accb, const float* __restrict__ pcnt,
                             const float* __restrict__ bl, float* __restrict__ out) {
  int b = blockIdx.x * 256 + threadIdx.x;
  if (b < NB) out[b] = accb[b] / fmaxf(pcnt[b], 1.0f) + bl[0];
}

// =================== host ===================
extern "C" void kernel_launch(void* const* d_in, const int* in_sizes, int n_in,
                              void* d_out, int out_size, void* d_ws, size_t ws_size,
                              hipStream_t stream) {
  const float* xt[7];
  for (int t = 0; t < 7; ++t) xt[t] = (const float*)d_in[t];
  const int* ei[14];
  for (int r = 0; r < 14; ++r) ei[r] = (const int*)d_in[7 + r];
  const int* batch = (const int*)d_in[21];
  const float* Wemb[7]; const float* bemb[7];
  for (int t = 0; t < 7; ++t) { Wemb[t] = (const float*)d_in[22 + 2 * t]; bemb[t] = (const float*)d_in[23 + 2 * t]; }
  const float* c_root[2] = {(const float*)d_in[36], (const float*)d_in[39]};
  const float* c_rel[2]  = {(const float*)d_in[37], (const float*)d_in[40]};
  const float* c_bias[2] = {(const float*)d_in[38], (const float*)d_in[41]};
  const float* ng[2] = {(const float*)d_in[42], (const float*)d_in[44]};
  const float* nbv[2] = {(const float*)d_in[43], (const float*)d_in[45]};
  const float* Wlin = (const float*)d_in[46];
  const float* blin = (const float*)d_in[47];
  float* out = (float*)d_out;

  char* base = (char*)d_ws;
  size_t off = 0;
  auto alloc = [&](size_t bytes) -> void* {
    void* p = base + off;
    off += (bytes + 255) & ~(size_t)255;
    return p;
  };
  __hip_bfloat16* Hb = (__hip_bfloat16*)alloc((size_t)N_L1 * HD * 2);
  float* AGR  = (float*)alloc((size_t)AGR_TOT * 4);
  int*   HEAD = (int*)alloc((size_t)CNT_TOT * 4);        // memset 0xFF -> -1
  float* ACC  = (float*)alloc((size_t)2 * NB * 4);       // memset 0 (ACC|PCNT)
  float* PCNT = ACC + NB;
  int2*  SRCNXT = (int2*)alloc((size_t)EDG_TOT * 8);
  float* WL1  = (float*)alloc((size_t)WL1_ROWS * 128 * 4);
  __hip_bfloat16* WT3 = (__hip_bfloat16*)alloc((size_t)6 * 16384 * 2);

  static const int l1_rels[12] = {0,1,2,3,4,5,6,7,8,11,12,13};

  // ---- memsets (2): HEAD=-1, ACC|PCNT=0 ----
  hipMemsetAsync(HEAD, 0xFF, (size_t)CNT_TOT * 4, stream);
  hipMemsetAsync(ACC, 0, (size_t)2 * NB * 4, stream);

  // ---- exch: linked-list adjacency + batch counts + weights (one kernel) ----
  XPack XP;
  int blk = 0;
  for (int q = 0; q < 12; ++q) {
    int r = l1_rels[q];
    XP.j[q].src = ei[r];
    XP.j[q].dst = ei[r] + REL_E[r];
    XP.j[q].coff = CNT_OFF[r];
    XP.j[q].eoff = EOFF12[q];
    XP.j[q].E = REL_E[r];
    XP.j[q].blk0 = blk;
    blk += (REL_E[r] + 255) / 256;
  }
  XP.bblk0 = blk; XP.batch = batch; XP.pcnt = PCNT; XP.nop = N_OP;
  blk += (N_OP + 255) / 256;
  XP.wstart = blk;
  for (int q = 0; q < 12; ++q) {
    int r = l1_rels[q]; int t = SRC_T[r];
    CombJob& J = XP.c[q];
    J.A = Wemb[t]; J.bin = bemb[t]; J.Mtx = c_rel[0] + (size_t)r * HD * HD;
    J.extra = nullptr;
    J.Wout = WL1 + (size_t)RELW[r] * 128;
    J.bout = WL1 + (size_t)RELI[r] * 128;
    J.F = TF[t];
  }
  for (int t = 0; t < 5; ++t) {
    CombJob& J = XP.c[12 + t];
    J.A = Wemb[t]; J.bin = bemb[t]; J.Mtx = c_root[0];
    J.extra = c_bias[0];
    J.Wout = WL1 + (size_t)ROOTW[t] * 128;
    J.bout = WL1 + (size_t)ROOTB[t] * 128;
    J.F = TF[t];
  }
  exch_k<<<blk + 23, 256, 0, stream>>>(XP, c_root[1], c_rel[1], WT3, HEAD, SRCNXT);

  // ---- gather: one thread per (rel,dst), traverse list, write pre-averaged AGR ----
  GPack GP;
  blk = 0;
  for (int q = 0; q < 12; ++q) {
    int r = l1_rels[q]; int t = SRC_T[r];
    GP.j[q].x = xt[t];
    GP.j[q].agr = AGR + AGR_OFF[r];
    GP.j[q].coff = CNT_OFF[r];
    GP.j[q].D = REL_DSZ[r];
    GP.j[q].F = TF[t];
    GP.j[q].blk0 = blk;
    blk += (REL_DSZ[r] + 255) / 256;
  }
  gather_all<<<blk, 256, 0, stream>>>(GP, HEAD, SRCNXT);

  // ---- layer 1: 4 rows/wave, vectorized s-loads ----
  L1v2 A;
  A.x0 = xt[0]; A.x1 = xt[1]; A.x2 = xt[2]; A.x3 = xt[3]; A.x4 = xt[4];
  A.AGR = AGR; A.WL1 = WL1; A.HEAD = HEAD;
  A.g = ng[0]; A.b = nbv[0]; A.Hb = (unsigned short*)Hb;
  layer1_v5<<<6252, 256, 0, stream>>>(A);

  // ---- layer 2: barrier-free, linked-list gather, pipelined prefetch ----
  l2_fused<<<(N_OP + 63) / 64, 256, 0, stream>>>(
      (const unsigned short*)Hb, (const unsigned short*)WT3,
      HEAD, SRCNXT, c_bias[1], ng[1], nbv[1], Wlin, batch, ACC, N_OP);

  // ---- final scale ----
  final_kernel<<<(NB + 255) / 256, 256, 0, stream>>>(ACC, PCNT, blin, out);
}